// Round 1
// baseline (635.417 us; speedup 1.0000x reference)
//
#include <hip/hip_runtime.h>
#include <hip/hip_bf16.h>

typedef __attribute__((ext_vector_type(8))) short short8;
typedef __attribute__((ext_vector_type(4))) float f32x4;

#define S_LEN 2048
#define DM 1024
#define NBATCH 8

__device__ __forceinline__ ushort f2b(float f) {
    union { float f; unsigned u; } a; a.f = f;
    unsigned u = a.u;
    u += 0x7fffu + ((u >> 16) & 1u);   // round-to-nearest-even
    return (ushort)(u >> 16);
}

#define GLDS(gp, lp) __builtin_amdgcn_global_load_lds( \
    (const __attribute__((address_space(1))) void*)(gp), \
    (__attribute__((address_space(3))) void*)(lp), 16, 0, 0)

// ---------------------------------------------------------------------------
// Generic B^T-layout MFMA GEMM: C[M,N] = A[M,K] * B[N,K]^T (+ bias[N])
// AMODE: 0 = A is bf16 (global_load_lds), 1 = A is fp32 (reg-stage + cvt)
// OMODE: 0 = fp32 C, 1 = bf16 C, 2 = bf16 C stored transposed (C[col*ldc+row])
// Tile 128x128, BK=32, 256 threads (4 waves, 2x2), 4x4 frags of 16x16x32.
// ---------------------------------------------------------------------------
template<int AMODE, int OMODE, bool HAS_BIAS>
__global__ __launch_bounds__(256) void gemm_bt(
    const void* __restrict__ Av, const ushort* __restrict__ B,
    void* __restrict__ Cv, const float* __restrict__ bias,
    int M, int N, int K, int lda, int ldb, int ldc,
    long long sA, long long sB, long long sC)
{
    __shared__ __align__(16) ushort lA[128 * 32];
    __shared__ __align__(16) ushort lB[128 * 32];

    const int t = threadIdx.x;
    const int wid = t >> 6, lane = t & 63;
    const int wm = wid >> 1, wn = wid & 1;
    const int z = blockIdx.z;
    const int bm = blockIdx.x, bn = blockIdx.y;
    const int rowA = bm * 128, rowB = bn * 128;

    const ushort* Bp = B + (size_t)z * sB;

    f32x4 acc[4][4] = {};

    const int rr = t >> 2;          // staging row 0..63 (per issue)
    const int cc = (t & 3) * 8;     // staging col (elements)
    const int nK = K >> 5;

    for (int kt = 0; kt < nK; ++kt) {
        const int k0 = kt * 32;
        if constexpr (AMODE == 0) {
            const ushort* Ap = (const ushort*)Av + (size_t)z * sA;
            const ushort* g0 = Ap + (size_t)(rowA + rr) * lda + k0 + cc;
            GLDS(g0, (char*)lA + wid * 1024);
            GLDS(g0 + (size_t)64 * lda, (char*)lA + 4096 + wid * 1024);
        } else {
            const float* Ap = (const float*)Av + (size_t)z * sA;
            const float* g0 = Ap + (size_t)(rowA + rr) * lda + k0 + cc;
            const float* g1 = g0 + (size_t)64 * lda;
            float4 x0 = *(const float4*)g0;
            float4 x1 = *(const float4*)(g0 + 4);
            float4 y0 = *(const float4*)g1;
            float4 y1 = *(const float4*)(g1 + 4);
            short8 p0, p1;
            p0[0]=(short)f2b(x0.x); p0[1]=(short)f2b(x0.y); p0[2]=(short)f2b(x0.z); p0[3]=(short)f2b(x0.w);
            p0[4]=(short)f2b(x1.x); p0[5]=(short)f2b(x1.y); p0[6]=(short)f2b(x1.z); p0[7]=(short)f2b(x1.w);
            p1[0]=(short)f2b(y0.x); p1[1]=(short)f2b(y0.y); p1[2]=(short)f2b(y0.z); p1[3]=(short)f2b(y0.w);
            p1[4]=(short)f2b(y1.x); p1[5]=(short)f2b(y1.y); p1[6]=(short)f2b(y1.z); p1[7]=(short)f2b(y1.w);
            *(short8*)((char*)lA + t * 16) = p0;
            *(short8*)((char*)lA + 4096 + t * 16) = p1;
        }
        {
            const ushort* g0 = Bp + (size_t)(rowB + rr) * ldb + k0 + cc;
            GLDS(g0, (char*)lB + wid * 1024);
            GLDS(g0 + (size_t)64 * ldb, (char*)lB + 4096 + wid * 1024);
        }
        __syncthreads();

        const int kq = (lane >> 4) * 8;
        const int r = lane & 15;
        short8 af[4], bfr[4];
#pragma unroll
        for (int m = 0; m < 4; m++)
            af[m] = *(const short8*)&lA[(wm * 64 + m * 16 + r) * 32 + kq];
#pragma unroll
        for (int n = 0; n < 4; n++)
            bfr[n] = *(const short8*)&lB[(wn * 64 + n * 16 + r) * 32 + kq];
#pragma unroll
        for (int m = 0; m < 4; m++)
#pragma unroll
            for (int n = 0; n < 4; n++)
                acc[m][n] = __builtin_amdgcn_mfma_f32_16x16x32_bf16(af[m], bfr[n], acc[m][n], 0, 0, 0);
        __syncthreads();
    }

    // epilogue: C row = (lane>>4)*4 + j, col = lane&15 within each 16x16 frag
    const int r = lane & 15;
    const int ro = (lane >> 4) * 4;
    const int colb = bn * 128 + wn * 64;
    const int rowb = bm * 128 + wm * 64;
    float bv[4];
    if constexpr (HAS_BIAS) {
#pragma unroll
        for (int n = 0; n < 4; n++) bv[n] = bias[colb + n * 16 + r];
    }

    if constexpr (OMODE == 0) {
        float* Cp = (float*)Cv + (size_t)z * sC;
#pragma unroll
        for (int m = 0; m < 4; m++)
#pragma unroll
            for (int n = 0; n < 4; n++) {
                const int col = colb + n * 16 + r;
#pragma unroll
                for (int j = 0; j < 4; j++) {
                    float vv = acc[m][n][j];
                    if constexpr (HAS_BIAS) vv += bv[n];
                    Cp[(size_t)(rowb + m * 16 + ro + j) * ldc + col] = vv;
                }
            }
    } else if constexpr (OMODE == 1) {
        ushort* Cp = (ushort*)Cv + (size_t)z * sC;
#pragma unroll
        for (int m = 0; m < 4; m++)
#pragma unroll
            for (int n = 0; n < 4; n++) {
                const int col = colb + n * 16 + r;
#pragma unroll
                for (int j = 0; j < 4; j++) {
                    float vv = acc[m][n][j];
                    if constexpr (HAS_BIAS) vv += bv[n];
                    Cp[(size_t)(rowb + m * 16 + ro + j) * ldc + col] = f2b(vv);
                }
            }
    } else {
        // transposed bf16 store: Cp[col*ldc + row]; 4 consecutive rows -> ushort4
        ushort* Cp = (ushort*)Cv + (size_t)z * sC;
#pragma unroll
        for (int m = 0; m < 4; m++)
#pragma unroll
            for (int n = 0; n < 4; n++) {
                const int col = colb + n * 16 + r;
                float v0 = acc[m][n][0], v1 = acc[m][n][1], v2 = acc[m][n][2], v3 = acc[m][n][3];
                if constexpr (HAS_BIAS) { v0 += bv[n]; v1 += bv[n]; v2 += bv[n]; v3 += bv[n]; }
                ushort4 u;
                u.x = f2b(v0); u.y = f2b(v1); u.z = f2b(v2); u.w = f2b(v3);
                *(ushort4*)&Cp[(size_t)col * ldc + rowb + m * 16 + ro] = u;
            }
    }
}

// ---------------------------------------------------------------------------
__global__ __launch_bounds__(256) void cast_f32_bf16_k(
    const float* __restrict__ in, ushort* __restrict__ outp, int n)
{
    int idx = (blockIdx.x * 256 + threadIdx.x) * 4;
    if (idx >= n) return;
    float4 f = *(const float4*)&in[idx];
    ushort4 u;
    u.x = f2b(f.x); u.y = f2b(f.y); u.z = f2b(f.z); u.w = f2b(f.w);
    *(ushort4*)&outp[idx] = u;
}

// ---------------------------------------------------------------------------
// In-place masked softmax over each row of w (fp32, row length 2048).
// x = score/32, masked -> -1e9 exactly, then row softmax.
// ---------------------------------------------------------------------------
__global__ __launch_bounds__(256) void softmax_rows(
    float* __restrict__ w, const int* __restrict__ mask)
{
    __shared__ float red[8];
    const int rid = blockIdx.x;            // b*S + q
    const int b = rid >> 11;               // S = 2048
    float* row = w + (size_t)rid * S_LEN;
    const int* mrow = mask + (size_t)b * S_LEN;
    const int t = threadIdx.x;
    const int wid = t >> 6, lane = t & 63;
    const float scale = 0.03125f;          // 1/sqrt(1024)

    float x[8];
    float mx = -3.0e38f;
#pragma unroll
    for (int i = 0; i < 2; i++) {
        const int idx = (t + i * 256) * 4;
        float4 s4 = *(const float4*)&row[idx];
        int4 m4 = *(const int4*)&mrow[idx];
        float* xp = &x[i * 4];
        xp[0] = (m4.x == 0) ? -1.0e9f : s4.x * scale;
        xp[1] = (m4.y == 0) ? -1.0e9f : s4.y * scale;
        xp[2] = (m4.z == 0) ? -1.0e9f : s4.z * scale;
        xp[3] = (m4.w == 0) ? -1.0e9f : s4.w * scale;
        mx = fmaxf(mx, fmaxf(fmaxf(xp[0], xp[1]), fmaxf(xp[2], xp[3])));
    }
#pragma unroll
    for (int off = 32; off; off >>= 1) mx = fmaxf(mx, __shfl_xor(mx, off));
    if (lane == 0) red[wid] = mx;
    __syncthreads();
    mx = fmaxf(fmaxf(red[0], red[1]), fmaxf(red[2], red[3]));

    float sum = 0.0f;
#pragma unroll
    for (int i = 0; i < 8; i++) { x[i] = __expf(x[i] - mx); sum += x[i]; }
#pragma unroll
    for (int off = 32; off; off >>= 1) sum += __shfl_xor(sum, off);
    if (lane == 0) red[4 + wid] = sum;
    __syncthreads();
    sum = red[4] + red[5] + red[6] + red[7];
    const float inv = 1.0f / sum;

#pragma unroll
    for (int i = 0; i < 2; i++) {
        const int idx = (t + i * 256) * 4;
        float4 o;
        o.x = x[i * 4 + 0] * inv; o.y = x[i * 4 + 1] * inv;
        o.z = x[i * 4 + 2] * inv; o.w = x[i * 4 + 3] * inv;
        *(float4*)&row[idx] = o;
    }
}

// ---------------------------------------------------------------------------
extern "C" void kernel_launch(void* const* d_in, const int* in_sizes, int n_in,
                              void* d_out, int out_size, void* d_ws, size_t ws_size,
                              hipStream_t stream)
{
    const float* q    = (const float*)d_in[0];
    const float* k    = (const float*)d_in[1];
    const float* v    = (const float*)d_in[2];
    const int*   mask = (const int*)d_in[3];
    const float* Wq   = (const float*)d_in[4];
    const float* bq   = (const float*)d_in[5];
    const float* Wout = (const float*)d_in[6];
    const float* bout = (const float*)d_in[7];

    float* out     = (float*)d_out;                             // [8,2048,1024]
    float* weights = out + (size_t)NBATCH * S_LEN * DM;         // [8,2048,2048]

    const size_t NTOK = (size_t)NBATCH * S_LEN;                 // 16384
    ushort* qp    = (ushort*)d_ws;                              // [16384,1024] bf16
    ushort* kp    = qp + NTOK * DM;
    ushort* vpT   = kp + NTOK * DM;                             // [8,1024,2048] bf16
    ushort* attn  = qp;                                         // alias: qp dead after scores
    ushort* Wqb   = vpT + NTOK * DM;
    ushort* Woutb = Wqb + (size_t)DM * DM;

    dim3 blk(256, 1, 1);

    cast_f32_bf16_k<<<dim3(1024, 1, 1), blk, 0, stream>>>(Wq, Wqb, DM * DM);
    cast_f32_bf16_k<<<dim3(1024, 1, 1), blk, 0, stream>>>(Wout, Woutb, DM * DM);

    // q,k projections: [16384,1024] x Wq[1024,1024]^T + bq -> bf16
    gemm_bt<1, 1, true><<<dim3(128, 8, 1), blk, 0, stream>>>(
        q, Wqb, qp, bq, 16384, 1024, 1024, 1024, 1024, 1024, 0, 0, 0);
    gemm_bt<1, 1, true><<<dim3(128, 8, 1), blk, 0, stream>>>(
        k, Wqb, kp, bq, 16384, 1024, 1024, 1024, 1024, 1024, 0, 0, 0);
    // v projection, stored transposed per batch: vpT[b][d][s]
    gemm_bt<1, 2, true><<<dim3(16, 8, NBATCH), blk, 0, stream>>>(
        v, Wqb, vpT, bq, 2048, 1024, 1024, 1024, 1024, 2048,
        (long long)S_LEN * DM, 0, (long long)DM * S_LEN);

    // scores = qp * kp^T  -> fp32 weights region of d_out
    gemm_bt<0, 0, false><<<dim3(16, 16, NBATCH), blk, 0, stream>>>(
        qp, kp, weights, nullptr, 2048, 2048, 1024, 1024, 1024, 2048,
        (long long)S_LEN * DM, (long long)S_LEN * DM, (long long)S_LEN * S_LEN);

    // masked softmax in place (scale 1/32, mask==0 -> -1e9)
    softmax_rows<<<dim3(NBATCH * S_LEN, 1, 1), blk, 0, stream>>>(weights, mask);

    // attn = weights * vp  (B = vpT in N x K layout) -> bf16
    gemm_bt<1, 1, false><<<dim3(16, 8, NBATCH), blk, 0, stream>>>(
        weights, vpT, attn, nullptr, 2048, 1024, 2048, 2048, 2048, 1024,
        (long long)S_LEN * S_LEN, (long long)DM * S_LEN, (long long)S_LEN * DM);

    // out = attn * Wout^T + bout -> fp32
    gemm_bt<0, 0, true><<<dim3(128, 8, 1), blk, 0, stream>>>(
        attn, Woutb, out, bout, 16384, 1024, 1024, 1024, 1024, 1024, 0, 0, 0);
}

// Round 2
// 629.702 us; speedup vs baseline: 1.0091x; 1.0091x over previous
//
#include <hip/hip_runtime.h>
#include <hip/hip_bf16.h>

typedef __attribute__((ext_vector_type(8))) short short8;
typedef __attribute__((ext_vector_type(4))) float f32x4;

#define S_LEN 2048
#define DM 1024
#define NBATCH 8

__device__ __forceinline__ ushort f2b(float f) {
    union { float f; unsigned u; } a; a.f = f;
    unsigned u = a.u;
    u += 0x7fffu + ((u >> 16) & 1u);   // round-to-nearest-even
    return (ushort)(u >> 16);
}

// packed f32 pair -> bf16x2 (compiler emits v_cvt_pk_bf16_f32; m240: don't hand-write)
__device__ __forceinline__ unsigned pkbf(float a, float b) {
    float2 t; t.x = a; t.y = b;
    __hip_bfloat162 h = __float22bfloat162_rn(t);
    union { __hip_bfloat162 h; unsigned u; } c; c.h = h;
    return c.u;
}

#define GLDS(gp, lp) __builtin_amdgcn_global_load_lds( \
    (const __attribute__((address_space(1))) void*)(gp), \
    (__attribute__((address_space(3))) void*)(lp), 16, 0, 0)

// ---------------------------------------------------------------------------
// Generic B^T-layout MFMA GEMM: C[M,N] = A[M,K] * B[N,K]^T (+ bias[N])
// AMODE: 0 = A is bf16 (global_load_lds), 1 = A is fp32 (reg-stage + cvt_pk)
// OMODE: 0 = fp32 C, 1 = bf16 C, 2 = bf16 C stored transposed (C[col*ldc+row])
// Tile 128x128, BK=32, 256 threads (4 waves, 2x2), 4x4 frags of 16x16x32.
// ---------------------------------------------------------------------------
template<int AMODE, int OMODE, bool HAS_BIAS>
__global__ __launch_bounds__(256) void gemm_bt(
    const void* __restrict__ Av, const ushort* __restrict__ B,
    void* __restrict__ Cv, const float* __restrict__ bias,
    int M, int N, int K, int lda, int ldb, int ldc,
    long long sA, long long sB, long long sC)
{
    __shared__ __align__(16) ushort lA[128 * 32];
    __shared__ __align__(16) ushort lB[128 * 32];

    const int t = threadIdx.x;
    const int wid = t >> 6, lane = t & 63;
    const int wm = wid >> 1, wn = wid & 1;
    const int z = blockIdx.z;
    const int bm = blockIdx.x, bn = blockIdx.y;
    const int rowA = bm * 128, rowB = bn * 128;

    const ushort* Bp = B + (size_t)z * sB;

    f32x4 acc[4][4] = {};

    const int rr = t >> 2;          // staging row 0..63 (per issue)
    const int cc = (t & 3) * 8;     // staging col (elements)
    const int nK = K >> 5;

    for (int kt = 0; kt < nK; ++kt) {
        const int k0 = kt * 32;
        if constexpr (AMODE == 0) {
            const ushort* Ap = (const ushort*)Av + (size_t)z * sA;
            const ushort* g0 = Ap + (size_t)(rowA + rr) * lda + k0 + cc;
            GLDS(g0, (char*)lA + wid * 1024);
            GLDS(g0 + (size_t)64 * lda, (char*)lA + 4096 + wid * 1024);
        } else {
            const float* Ap = (const float*)Av + (size_t)z * sA;
            const float* g0 = Ap + (size_t)(rowA + rr) * lda + k0 + cc;
            const float* g1 = g0 + (size_t)64 * lda;
            float4 x0 = *(const float4*)g0;
            float4 x1 = *(const float4*)(g0 + 4);
            float4 y0 = *(const float4*)g1;
            float4 y1 = *(const float4*)(g1 + 4);
            uint4 p0, p1;
            p0.x = pkbf(x0.x, x0.y); p0.y = pkbf(x0.z, x0.w);
            p0.z = pkbf(x1.x, x1.y); p0.w = pkbf(x1.z, x1.w);
            p1.x = pkbf(y0.x, y0.y); p1.y = pkbf(y0.z, y0.w);
            p1.z = pkbf(y1.x, y1.y); p1.w = pkbf(y1.z, y1.w);
            *(uint4*)((char*)lA + t * 16) = p0;
            *(uint4*)((char*)lA + 4096 + t * 16) = p1;
        }
        {
            const ushort* g0 = Bp + (size_t)(rowB + rr) * ldb + k0 + cc;
            GLDS(g0, (char*)lB + wid * 1024);
            GLDS(g0 + (size_t)64 * ldb, (char*)lB + 4096 + wid * 1024);
        }
        __syncthreads();

        const int kq = (lane >> 4) * 8;
        const int r = lane & 15;
        short8 af[4], bfr[4];
#pragma unroll
        for (int m = 0; m < 4; m++)
            af[m] = *(const short8*)&lA[(wm * 64 + m * 16 + r) * 32 + kq];
#pragma unroll
        for (int n = 0; n < 4; n++)
            bfr[n] = *(const short8*)&lB[(wn * 64 + n * 16 + r) * 32 + kq];
#pragma unroll
        for (int m = 0; m < 4; m++)
#pragma unroll
            for (int n = 0; n < 4; n++)
                acc[m][n] = __builtin_amdgcn_mfma_f32_16x16x32_bf16(af[m], bfr[n], acc[m][n], 0, 0, 0);
        __syncthreads();
    }

    // epilogue: C row = (lane>>4)*4 + j, col = lane&15 within each 16x16 frag
    const int r = lane & 15;
    const int ro = (lane >> 4) * 4;
    const int colb = bn * 128 + wn * 64;
    const int rowb = bm * 128 + wm * 64;
    float bv[4];
    if constexpr (HAS_BIAS) {
#pragma unroll
        for (int n = 0; n < 4; n++) bv[n] = bias[colb + n * 16 + r];
    }

    if constexpr (OMODE == 0) {
        float* Cp = (float*)Cv + (size_t)z * sC;
#pragma unroll
        for (int m = 0; m < 4; m++)
#pragma unroll
            for (int n = 0; n < 4; n++) {
                const int col = colb + n * 16 + r;
#pragma unroll
                for (int j = 0; j < 4; j++) {
                    float vv = acc[m][n][j];
                    if constexpr (HAS_BIAS) vv += bv[n];
                    Cp[(size_t)(rowb + m * 16 + ro + j) * ldc + col] = vv;
                }
            }
    } else if constexpr (OMODE == 1) {
        ushort* Cp = (ushort*)Cv + (size_t)z * sC;
#pragma unroll
        for (int m = 0; m < 4; m++)
#pragma unroll
            for (int n = 0; n < 4; n++) {
                const int col = colb + n * 16 + r;
#pragma unroll
                for (int j = 0; j < 4; j++) {
                    float vv = acc[m][n][j];
                    if constexpr (HAS_BIAS) vv += bv[n];
                    Cp[(size_t)(rowb + m * 16 + ro + j) * ldc + col] = f2b(vv);
                }
            }
    } else {
        // transposed bf16 store: Cp[col*ldc + row]; 4 consecutive rows -> ushort4
        ushort* Cp = (ushort*)Cv + (size_t)z * sC;
#pragma unroll
        for (int m = 0; m < 4; m++)
#pragma unroll
            for (int n = 0; n < 4; n++) {
                const int col = colb + n * 16 + r;
                float v0 = acc[m][n][0], v1 = acc[m][n][1], v2 = acc[m][n][2], v3 = acc[m][n][3];
                if constexpr (HAS_BIAS) { v0 += bv[n]; v1 += bv[n]; v2 += bv[n]; v3 += bv[n]; }
                ushort4 u;
                u.x = f2b(v0); u.y = f2b(v1); u.z = f2b(v2); u.w = f2b(v3);
                *(ushort4*)&Cp[(size_t)col * ldc + rowb + m * 16 + ro] = u;
            }
    }
}

// ---------------------------------------------------------------------------
__global__ __launch_bounds__(256) void cast_f32_bf16_k(
    const float* __restrict__ in, ushort* __restrict__ outp, int n)
{
    int idx = (blockIdx.x * 256 + threadIdx.x) * 4;
    if (idx >= n) return;
    float4 f = *(const float4*)&in[idx];
    ushort4 u;
    u.x = f2b(f.x); u.y = f2b(f.y); u.z = f2b(f.z); u.w = f2b(f.w);
    *(ushort4*)&outp[idx] = u;
}

// ---------------------------------------------------------------------------
// In-place masked softmax over each row of w (fp32, row length 2048).
// x = score/32, masked -> -1e9 exactly, then row softmax.
// Also writes a bf16 copy of the normalized weights to wb (for the PV GEMM).
// ---------------------------------------------------------------------------
__global__ __launch_bounds__(256) void softmax_rows(
    float* __restrict__ w, const int* __restrict__ mask, ushort* __restrict__ wb)
{
    __shared__ float red[8];
    const int rid = blockIdx.x;            // b*S + q
    const int b = rid >> 11;               // S = 2048
    float* row = w + (size_t)rid * S_LEN;
    ushort* brow = wb + (size_t)rid * S_LEN;
    const int* mrow = mask + (size_t)b * S_LEN;
    const int t = threadIdx.x;
    const int wid = t >> 6, lane = t & 63;
    const float scale = 0.03125f;          // 1/sqrt(1024)

    float x[8];
    float mx = -3.0e38f;
#pragma unroll
    for (int i = 0; i < 2; i++) {
        const int idx = (t + i * 256) * 4;
        float4 s4 = *(const float4*)&row[idx];
        int4 m4 = *(const int4*)&mrow[idx];
        float* xp = &x[i * 4];
        xp[0] = (m4.x == 0) ? -1.0e9f : s4.x * scale;
        xp[1] = (m4.y == 0) ? -1.0e9f : s4.y * scale;
        xp[2] = (m4.z == 0) ? -1.0e9f : s4.z * scale;
        xp[3] = (m4.w == 0) ? -1.0e9f : s4.w * scale;
        mx = fmaxf(mx, fmaxf(fmaxf(xp[0], xp[1]), fmaxf(xp[2], xp[3])));
    }
#pragma unroll
    for (int off = 32; off; off >>= 1) mx = fmaxf(mx, __shfl_xor(mx, off));
    if (lane == 0) red[wid] = mx;
    __syncthreads();
    mx = fmaxf(fmaxf(red[0], red[1]), fmaxf(red[2], red[3]));

    float sum = 0.0f;
#pragma unroll
    for (int i = 0; i < 8; i++) { x[i] = __expf(x[i] - mx); sum += x[i]; }
#pragma unroll
    for (int off = 32; off; off >>= 1) sum += __shfl_xor(sum, off);
    if (lane == 0) red[4 + wid] = sum;
    __syncthreads();
    sum = red[4] + red[5] + red[6] + red[7];
    const float inv = 1.0f / sum;

#pragma unroll
    for (int i = 0; i < 2; i++) {
        const int idx = (t + i * 256) * 4;
        float4 o;
        o.x = x[i * 4 + 0] * inv; o.y = x[i * 4 + 1] * inv;
        o.z = x[i * 4 + 2] * inv; o.w = x[i * 4 + 3] * inv;
        *(float4*)&row[idx] = o;
        uint2 ub;
        ub.x = pkbf(o.x, o.y);
        ub.y = pkbf(o.z, o.w);
        *(uint2*)&brow[idx] = ub;
    }
}

// ---------------------------------------------------------------------------
extern "C" void kernel_launch(void* const* d_in, const int* in_sizes, int n_in,
                              void* d_out, int out_size, void* d_ws, size_t ws_size,
                              hipStream_t stream)
{
    const float* q    = (const float*)d_in[0];
    const float* k    = (const float*)d_in[1];
    const float* v    = (const float*)d_in[2];
    const int*   mask = (const int*)d_in[3];
    const float* Wq   = (const float*)d_in[4];
    const float* bq   = (const float*)d_in[5];
    const float* Wout = (const float*)d_in[6];
    const float* bout = (const float*)d_in[7];

    float* out     = (float*)d_out;                             // [8,2048,1024] fp32
    float* weights = out + (size_t)NBATCH * S_LEN * DM;         // [8,2048,2048] fp32

    // bf16 weights scratch overlays the `out` region (67.1 MB == 67.1 MB):
    // dead until the final out-projection overwrites it.
    ushort* wbf = (ushort*)d_out;

    const size_t NTOK = (size_t)NBATCH * S_LEN;                 // 16384
    ushort* qp    = (ushort*)d_ws;                              // [16384,1024] bf16
    ushort* kp    = qp + NTOK * DM;
    ushort* vpT   = kp + NTOK * DM;                             // [8,1024,2048] bf16
    ushort* attn  = qp;                                         // alias: qp dead after scores
    ushort* Wqb   = vpT + NTOK * DM;
    ushort* Woutb = Wqb + (size_t)DM * DM;

    dim3 blk(256, 1, 1);

    cast_f32_bf16_k<<<dim3(1024, 1, 1), blk, 0, stream>>>(Wq, Wqb, DM * DM);
    cast_f32_bf16_k<<<dim3(1024, 1, 1), blk, 0, stream>>>(Wout, Woutb, DM * DM);

    // q,k projections: [16384,1024] x Wq[1024,1024]^T + bq -> bf16
    gemm_bt<1, 1, true><<<dim3(128, 8, 1), blk, 0, stream>>>(
        q, Wqb, qp, bq, 16384, 1024, 1024, 1024, 1024, 1024, 0, 0, 0);
    gemm_bt<1, 1, true><<<dim3(128, 8, 1), blk, 0, stream>>>(
        k, Wqb, kp, bq, 16384, 1024, 1024, 1024, 1024, 1024, 0, 0, 0);
    // v projection, stored transposed per batch: vpT[b][d][s]
    gemm_bt<1, 2, true><<<dim3(16, 8, NBATCH), blk, 0, stream>>>(
        v, Wqb, vpT, bq, 2048, 1024, 1024, 1024, 1024, 2048,
        (long long)S_LEN * DM, 0, (long long)DM * S_LEN);

    // scores = qp * kp^T  -> fp32 weights region of d_out
    gemm_bt<0, 0, false><<<dim3(16, 16, NBATCH), blk, 0, stream>>>(
        qp, kp, weights, nullptr, 2048, 2048, 1024, 1024, 1024, 2048,
        (long long)S_LEN * DM, (long long)S_LEN * DM, (long long)S_LEN * S_LEN);

    // masked softmax in place (scale 1/32, mask==0 -> -1e9), bf16 copy -> wbf
    softmax_rows<<<dim3(NBATCH * S_LEN, 1, 1), blk, 0, stream>>>(weights, mask, wbf);

    // attn = softmax(weights) * vp   (A = wbf bf16, B = vpT in N x K layout)
    gemm_bt<0, 1, false><<<dim3(16, 8, NBATCH), blk, 0, stream>>>(
        wbf, vpT, attn, nullptr, 2048, 1024, 2048, 2048, 2048, 1024,
        (long long)S_LEN * S_LEN, (long long)DM * S_LEN, (long long)S_LEN * DM);

    // out = attn * Wout^T + bout -> fp32 (overwrites the wbf overlay)
    gemm_bt<0, 0, true><<<dim3(128, 8, 1), blk, 0, stream>>>(
        attn, Woutb, out, bout, 16384, 1024, 1024, 1024, 1024, 1024, 0, 0, 0);
}

// Round 3
// 582.686 us; speedup vs baseline: 1.0905x; 1.0807x over previous
//
#include <hip/hip_runtime.h>
#include <hip/hip_bf16.h>

typedef __attribute__((ext_vector_type(8))) short short8;
typedef __attribute__((ext_vector_type(4))) float f32x4;

#define S_LEN 2048
#define DM 1024
#define NBATCH 8

__device__ __forceinline__ ushort f2b(float f) {
    union { float f; unsigned u; } a; a.f = f;
    unsigned u = a.u;
    u += 0x7fffu + ((u >> 16) & 1u);   // round-to-nearest-even
    return (ushort)(u >> 16);
}

// packed f32 pair -> bf16x2 (compiler emits v_cvt_pk_bf16_f32)
__device__ __forceinline__ unsigned pkbf(float a, float b) {
    float2 t; t.x = a; t.y = b;
    __hip_bfloat162 h = __float22bfloat162_rn(t);
    union { __hip_bfloat162 h; unsigned u; } c; c.h = h;
    return c.u;
}

#define GLDS(gp, lp) __builtin_amdgcn_global_load_lds( \
    (const __attribute__((address_space(1))) void*)(gp), \
    (__attribute__((address_space(3))) void*)(lp), 16, 0, 0)

// ---------------------------------------------------------------------------
// B^T-layout MFMA GEMM: C[M,N] = A[M,K] * B[N,K]^T (+ bias[N]); A,B bf16.
// OMODE: 0 = fp32 C, 1 = bf16 C, 2 = bf16 C stored transposed (C[col*ldc+row])
// Tile 128x128, BK=32, 256 threads (4 waves, 2x2), 4x4 frags of 16x16x32.
// T1: bijective XCD chunking, bn-fastest within chunk (A-panel L2 sharing).
// ---------------------------------------------------------------------------
template<int OMODE, bool HAS_BIAS>
__global__ __launch_bounds__(256) void gemm_bt(
    const ushort* __restrict__ A, const ushort* __restrict__ B,
    void* __restrict__ Cv, const float* __restrict__ bias,
    int K, int lda, int ldb, int ldc,
    long long sA, long long sB, long long sC)
{
    __shared__ __align__(16) ushort lA[128 * 32];
    __shared__ __align__(16) ushort lB[128 * 32];

    const int t = threadIdx.x;
    const int wid = t >> 6, lane = t & 63;
    const int wm = wid >> 1, wn = wid & 1;
    const int z = blockIdx.z;

    // --- XCD-aware bijective swizzle (m204), bn-fastest within XCD chunk ---
    const int gx = gridDim.x, gy = gridDim.y;
    const int nwg = gx * gy;
    const int lid = blockIdx.y * gx + blockIdx.x;     // hw dispatch order in z-plane
    const int qq = nwg >> 3, r8 = nwg & 7;
    const int xcd = lid & 7, off = lid >> 3;
    const int w = (xcd < r8 ? xcd * (qq + 1) : r8 * (qq + 1) + (xcd - r8) * qq) + off;
    const int bm = w / gy, bn = w % gy;

    const int rowA = bm * 128, rowB = bn * 128;

    const ushort* Ap = A + (size_t)z * sA;
    const ushort* Bp = B + (size_t)z * sB;

    f32x4 acc[4][4] = {};

    const int rr = t >> 2;          // staging row 0..63 (per issue)
    const int cc = (t & 3) * 8;     // staging col (elements)
    const int nK = K >> 5;

    for (int kt = 0; kt < nK; ++kt) {
        const int k0 = kt * 32;
        {
            const ushort* g0 = Ap + (size_t)(rowA + rr) * lda + k0 + cc;
            GLDS(g0, (char*)lA + wid * 1024);
            GLDS(g0 + (size_t)64 * lda, (char*)lA + 4096 + wid * 1024);
        }
        {
            const ushort* g0 = Bp + (size_t)(rowB + rr) * ldb + k0 + cc;
            GLDS(g0, (char*)lB + wid * 1024);
            GLDS(g0 + (size_t)64 * ldb, (char*)lB + 4096 + wid * 1024);
        }
        __syncthreads();

        const int kq = (lane >> 4) * 8;
        const int r = lane & 15;
        short8 af[4], bfr[4];
#pragma unroll
        for (int m = 0; m < 4; m++)
            af[m] = *(const short8*)&lA[(wm * 64 + m * 16 + r) * 32 + kq];
#pragma unroll
        for (int n = 0; n < 4; n++)
            bfr[n] = *(const short8*)&lB[(wn * 64 + n * 16 + r) * 32 + kq];
#pragma unroll
        for (int m = 0; m < 4; m++)
#pragma unroll
            for (int n = 0; n < 4; n++)
                acc[m][n] = __builtin_amdgcn_mfma_f32_16x16x32_bf16(af[m], bfr[n], acc[m][n], 0, 0, 0);
        __syncthreads();
    }

    // epilogue: C row = (lane>>4)*4 + j, col = lane&15 within each 16x16 frag
    const int r = lane & 15;
    const int ro = (lane >> 4) * 4;
    const int colb = bn * 128 + wn * 64;
    const int rowb = bm * 128 + wm * 64;
    float bv[4];
    if constexpr (HAS_BIAS) {
#pragma unroll
        for (int n = 0; n < 4; n++) bv[n] = bias[colb + n * 16 + r];
    }

    if constexpr (OMODE == 0) {
        float* Cp = (float*)Cv + (size_t)z * sC;
#pragma unroll
        for (int m = 0; m < 4; m++)
#pragma unroll
            for (int n = 0; n < 4; n++) {
                const int col = colb + n * 16 + r;
#pragma unroll
                for (int j = 0; j < 4; j++) {
                    float vv = acc[m][n][j];
                    if constexpr (HAS_BIAS) vv += bv[n];
                    Cp[(size_t)(rowb + m * 16 + ro + j) * ldc + col] = vv;
                }
            }
    } else if constexpr (OMODE == 1) {
        ushort* Cp = (ushort*)Cv + (size_t)z * sC;
#pragma unroll
        for (int m = 0; m < 4; m++)
#pragma unroll
            for (int n = 0; n < 4; n++) {
                const int col = colb + n * 16 + r;
#pragma unroll
                for (int j = 0; j < 4; j++) {
                    float vv = acc[m][n][j];
                    if constexpr (HAS_BIAS) vv += bv[n];
                    Cp[(size_t)(rowb + m * 16 + ro + j) * ldc + col] = f2b(vv);
                }
            }
    } else {
        // transposed bf16 store: Cp[col*ldc + row]; 4 consecutive rows -> ushort4
        ushort* Cp = (ushort*)Cv + (size_t)z * sC;
#pragma unroll
        for (int m = 0; m < 4; m++)
#pragma unroll
            for (int n = 0; n < 4; n++) {
                const int col = colb + n * 16 + r;
                float v0 = acc[m][n][0], v1 = acc[m][n][1], v2 = acc[m][n][2], v3 = acc[m][n][3];
                if constexpr (HAS_BIAS) { v0 += bv[n]; v1 += bv[n]; v2 += bv[n]; v3 += bv[n]; }
                ushort4 u;
                u.x = f2b(v0); u.y = f2b(v1); u.z = f2b(v2); u.w = f2b(v3);
                *(ushort4*)&Cp[(size_t)col * ldc + rowb + m * 16 + ro] = u;
            }
    }
}

// ---------------------------------------------------------------------------
__global__ __launch_bounds__(256) void cast_f32_bf16_k(
    const float* __restrict__ in, ushort* __restrict__ outp, int n)
{
    int idx = (blockIdx.x * 256 + threadIdx.x) * 4;
    if (idx >= n) return;
    float4 f = *(const float4*)&in[idx];
    uint2 u; u.x = pkbf(f.x, f.y); u.y = pkbf(f.z, f.w);
    *(uint2*)&outp[idx] = u;
}

// cast q,k,v -> contiguous bf16 [3][n_each]; blockIdx.y selects the input
__global__ __launch_bounds__(256) void cast3_k(
    const float* __restrict__ q, const float* __restrict__ k,
    const float* __restrict__ v, ushort* __restrict__ outp, int n_each)
{
    const float* src = (blockIdx.y == 0) ? q : (blockIdx.y == 1) ? k : v;
    ushort* dst = outp + (size_t)blockIdx.y * n_each;
    const int stride = gridDim.x * 256 * 4;
    for (int idx = (blockIdx.x * 256 + threadIdx.x) * 4; idx < n_each; idx += stride) {
        float4 f = *(const float4*)&src[idx];
        uint2 u; u.x = pkbf(f.x, f.y); u.y = pkbf(f.z, f.w);
        *(uint2*)&dst[idx] = u;
    }
}

// ---------------------------------------------------------------------------
// In-place masked softmax over each row of w (fp32, row length 2048).
// x = score/32, masked -> -1e9 exactly, then row softmax. bf16 copy -> wb.
// ---------------------------------------------------------------------------
__global__ __launch_bounds__(256) void softmax_rows(
    float* __restrict__ w, const int* __restrict__ mask, ushort* __restrict__ wb)
{
    __shared__ float red[8];
    const int rid = blockIdx.x;            // b*S + q
    const int b = rid >> 11;               // S = 2048
    float* row = w + (size_t)rid * S_LEN;
    ushort* brow = wb + (size_t)rid * S_LEN;
    const int* mrow = mask + (size_t)b * S_LEN;
    const int t = threadIdx.x;
    const int wid = t >> 6, lane = t & 63;
    const float scale = 0.03125f;          // 1/sqrt(1024)

    float x[8];
    float mx = -3.0e38f;
#pragma unroll
    for (int i = 0; i < 2; i++) {
        const int idx = (t + i * 256) * 4;
        float4 s4 = *(const float4*)&row[idx];
        int4 m4 = *(const int4*)&mrow[idx];
        float* xp = &x[i * 4];
        xp[0] = (m4.x == 0) ? -1.0e9f : s4.x * scale;
        xp[1] = (m4.y == 0) ? -1.0e9f : s4.y * scale;
        xp[2] = (m4.z == 0) ? -1.0e9f : s4.z * scale;
        xp[3] = (m4.w == 0) ? -1.0e9f : s4.w * scale;
        mx = fmaxf(mx, fmaxf(fmaxf(xp[0], xp[1]), fmaxf(xp[2], xp[3])));
    }
#pragma unroll
    for (int off = 32; off; off >>= 1) mx = fmaxf(mx, __shfl_xor(mx, off));
    if (lane == 0) red[wid] = mx;
    __syncthreads();
    mx = fmaxf(fmaxf(red[0], red[1]), fmaxf(red[2], red[3]));

    float sum = 0.0f;
#pragma unroll
    for (int i = 0; i < 8; i++) { x[i] = __expf(x[i] - mx); sum += x[i]; }
#pragma unroll
    for (int off = 32; off; off >>= 1) sum += __shfl_xor(sum, off);
    if (lane == 0) red[4 + wid] = sum;
    __syncthreads();
    sum = red[4] + red[5] + red[6] + red[7];
    const float inv = 1.0f / sum;

#pragma unroll
    for (int i = 0; i < 2; i++) {
        const int idx = (t + i * 256) * 4;
        float4 o;
        o.x = x[i * 4 + 0] * inv; o.y = x[i * 4 + 1] * inv;
        o.z = x[i * 4 + 2] * inv; o.w = x[i * 4 + 3] * inv;
        *(float4*)&row[idx] = o;
        uint2 ub;
        ub.x = pkbf(o.x, o.y);
        ub.y = pkbf(o.z, o.w);
        *(uint2*)&brow[idx] = ub;
    }
}

// ---------------------------------------------------------------------------
extern "C" void kernel_launch(void* const* d_in, const int* in_sizes, int n_in,
                              void* d_out, int out_size, void* d_ws, size_t ws_size,
                              hipStream_t stream)
{
    const float* q    = (const float*)d_in[0];
    const float* k    = (const float*)d_in[1];
    const float* v    = (const float*)d_in[2];
    const int*   mask = (const int*)d_in[3];
    const float* Wq   = (const float*)d_in[4];
    const float* bq   = (const float*)d_in[5];
    const float* Wout = (const float*)d_in[6];
    const float* bout = (const float*)d_in[7];

    float* out     = (float*)d_out;                             // [8,2048,1024] fp32
    float* weights = out + (size_t)NBATCH * S_LEN * DM;         // [8,2048,2048] fp32

    const size_t NTOK = (size_t)NBATCH * S_LEN;                 // 16384

    // Overlays of dead d_out regions:
    // 1) bf16 q/k/v casts live in the weights region (134 MB; dead until scores)
    ushort* qkvb = (ushort*)weights;                            // [3][16384*1024] bf16
    ushort* qb = qkvb;
    ushort* kb = qb + NTOK * DM;
    ushort* vb = kb + NTOK * DM;
    // 2) bf16 softmax weights live in the out region (67 MB; dead until outproj)
    ushort* wbf = (ushort*)d_out;

    ushort* qp    = (ushort*)d_ws;                              // [16384,1024] bf16
    ushort* kp    = qp + NTOK * DM;
    ushort* vpT   = kp + NTOK * DM;                             // [8,1024,2048] bf16
    ushort* attn  = qp;                                         // alias: qp dead after scores
    ushort* Wqb   = vpT + NTOK * DM;
    ushort* Woutb = Wqb + (size_t)DM * DM;

    dim3 blk(256, 1, 1);

    cast_f32_bf16_k<<<dim3(1024, 1, 1), blk, 0, stream>>>(Wq, Wqb, DM * DM);
    cast_f32_bf16_k<<<dim3(1024, 1, 1), blk, 0, stream>>>(Wout, Woutb, DM * DM);
    cast3_k<<<dim3(2048, 3, 1), blk, 0, stream>>>(q, k, v, qkvb, (int)(NTOK * DM));

    // q,k projections: [16384,1024] x Wq[1024,1024]^T + bq -> bf16
    gemm_bt<1, true><<<dim3(128, 8, 1), blk, 0, stream>>>(
        qb, Wqb, qp, bq, 1024, 1024, 1024, 1024, 0, 0, 0);
    gemm_bt<1, true><<<dim3(128, 8, 1), blk, 0, stream>>>(
        kb, Wqb, kp, bq, 1024, 1024, 1024, 1024, 0, 0, 0);
    // v projection, stored transposed per batch: vpT[b][d][s]
    gemm_bt<2, true><<<dim3(16, 8, NBATCH), blk, 0, stream>>>(
        vb, Wqb, vpT, bq, 1024, 1024, 1024, 2048,
        (long long)S_LEN * DM, 0, (long long)DM * S_LEN);

    // scores = qp * kp^T -> fp32 weights region of d_out (overwrites qkvb: dead)
    gemm_bt<0, false><<<dim3(16, 16, NBATCH), blk, 0, stream>>>(
        qp, kp, weights, nullptr, 1024, 1024, 1024, 2048,
        (long long)S_LEN * DM, (long long)S_LEN * DM, (long long)S_LEN * S_LEN);

    // masked softmax in place (scale 1/32, mask==0 -> -1e9), bf16 copy -> wbf
    softmax_rows<<<dim3(NBATCH * S_LEN, 1, 1), blk, 0, stream>>>(weights, mask, wbf);

    // attn = softmax(weights) * vp   (A = wbf bf16, B = vpT in N x K layout)
    gemm_bt<1, false><<<dim3(16, 8, NBATCH), blk, 0, stream>>>(
        wbf, vpT, attn, nullptr, 2048, 2048, 2048, 1024,
        (long long)S_LEN * S_LEN, (long long)DM * S_LEN, (long long)S_LEN * DM);

    // out = attn * Wout^T + bout -> fp32 (overwrites the wbf overlay)
    gemm_bt<0, true><<<dim3(128, 8, 1), blk, 0, stream>>>(
        attn, Woutb, out, bout, 1024, 1024, 1024, 1024, 0, 0, 0);
}

// Round 4
// 529.215 us; speedup vs baseline: 1.2007x; 1.1010x over previous
//
#include <hip/hip_runtime.h>
#include <hip/hip_bf16.h>

typedef __attribute__((ext_vector_type(8))) short short8;
typedef __attribute__((ext_vector_type(4))) float f32x4;

#define S_LEN 2048
#define DM 1024
#define NBATCH 8

__device__ __forceinline__ ushort f2b(float f) {
    union { float f; unsigned u; } a; a.f = f;
    unsigned u = a.u;
    u += 0x7fffu + ((u >> 16) & 1u);   // round-to-nearest-even
    return (ushort)(u >> 16);
}

// packed f32 pair -> bf16x2 (compiler emits v_cvt_pk_bf16_f32)
__device__ __forceinline__ unsigned pkbf(float a, float b) {
    float2 t; t.x = a; t.y = b;
    __hip_bfloat162 h = __float22bfloat162_rn(t);
    union { __hip_bfloat162 h; unsigned u; } c; c.h = h;
    return c.u;
}

#define GLDS(gp, lp) __builtin_amdgcn_global_load_lds( \
    (const __attribute__((address_space(1))) void*)(gp), \
    (__attribute__((address_space(3))) void*)(lp), 16, 0, 0)

// ---------------------------------------------------------------------------
// 256x256 double-buffered MFMA GEMM: C[M,N] = A[M,K] * B[N,K]^T (+ bias[N]).
// A,B bf16. BK=32. 512 threads = 8 waves (2M x 4N), per-wave 128x64 output.
// 2-phase schedule: STAGE(next tile) early, compute cur, __syncthreads drain.
// LDS tiles [256][32] bf16, XOR-swizzled (write-linear / source-preswizzled /
// read-swizzled, rule #21): byte ^= ((row&3)<<4)  ->  8-way -> 4-way conflicts.
// OMODE: 0 = fp32 C, 1 = bf16 C, 2 = bf16 C stored transposed (C[col*ldc+row])
// ---------------------------------------------------------------------------
template<int OMODE, bool HAS_BIAS>
__global__ __launch_bounds__(512, 2) void gemm256(
    const ushort* __restrict__ A, const ushort* __restrict__ B,
    void* __restrict__ Cv, const float* __restrict__ bias,
    int K, int lda, int ldb, int ldc,
    long long sA, long long sB, long long sC)
{
    __shared__ __align__(16) ushort lA[2][256 * 32];   // 2 x 16 KB
    __shared__ __align__(16) ushort lB[2][256 * 32];   // 2 x 16 KB

    const int t = threadIdx.x;
    const int wid = t >> 6, lane = t & 63;
    const int wm = wid >> 2, wn = wid & 3;             // 2 x 4 wave grid
    const int z = blockIdx.z;

    // --- XCD-aware bijective swizzle (m204), bn-fastest within XCD chunk ---
    const int gx = gridDim.x, gy = gridDim.y;
    const int nwg = gx * gy;
    const int lid = blockIdx.y * gx + blockIdx.x;
    const int qq = nwg >> 3, r8 = nwg & 7;
    const int xcd = lid & 7, off = lid >> 3;
    const int w = (xcd < r8 ? xcd * (qq + 1) : r8 * (qq + 1) + (xcd - r8) * qq) + off;
    const int bm = w / gy, bn = w % gy;

    const ushort* Ap = A + (size_t)z * sA + (size_t)(bm * 256) * lda;
    const ushort* Bp = B + (size_t)z * sB + (size_t)(bn * 256) * ldb;

    f32x4 acc[8][4] = {};

    // staging map (per 8-KB issue): row = t>>2 (0..127), 16B block;
    // source col pre-swizzled so linear LDS write yields swizzled layout
    const int srow = t >> 2;
    const int scol = ((t & 3) ^ ((t >> 2) & 3)) * 8;   // elements
    const int nK = K >> 5;

    // read map: lane r = lane&15 selects row, (lane>>4) selects 16B k-block
    const int r = lane & 15;
    const int cb = ((lane >> 4) * 16) ^ ((r & 3) << 4); // swizzled col byte

    int cur = 0;
    {   // prologue: stage tile 0 into buf 0
        const ushort* ga = Ap + (size_t)srow * lda + scol;
        GLDS(ga, (char*)lA[0] + wid * 1024);
        GLDS(ga + (size_t)128 * lda, (char*)lA[0] + 8192 + wid * 1024);
        const ushort* gb = Bp + (size_t)srow * ldb + scol;
        GLDS(gb, (char*)lB[0] + wid * 1024);
        GLDS(gb + (size_t)128 * ldb, (char*)lB[0] + 8192 + wid * 1024);
    }
    __syncthreads();

    for (int kt = 0; kt < nK; ++kt) {
        if (kt + 1 < nK) {   // issue next-tile loads early (fly under compute)
            const int k0 = (kt + 1) * 32;
            const ushort* ga = Ap + (size_t)srow * lda + k0 + scol;
            char* dA = (char*)lA[cur ^ 1];
            GLDS(ga, dA + wid * 1024);
            GLDS(ga + (size_t)128 * lda, dA + 8192 + wid * 1024);
            const ushort* gb = Bp + (size_t)srow * ldb + k0 + scol;
            char* dB = (char*)lB[cur ^ 1];
            GLDS(gb, dB + wid * 1024);
            GLDS(gb + (size_t)128 * ldb, dB + 8192 + wid * 1024);
        }
        const char* la = (const char*)lA[cur];
        const char* lb = (const char*)lB[cur];
        short8 af[8], bfr[4];
#pragma unroll
        for (int m = 0; m < 8; m++) {
            const int row = wm * 128 + m * 16 + r;
            af[m] = *(const short8*)(la + row * 64 + cb);
        }
#pragma unroll
        for (int n = 0; n < 4; n++) {
            const int row = wn * 64 + n * 16 + r;
            bfr[n] = *(const short8*)(lb + row * 64 + cb);
        }
#pragma unroll
        for (int m = 0; m < 8; m++)
#pragma unroll
            for (int n = 0; n < 4; n++)
                acc[m][n] = __builtin_amdgcn_mfma_f32_16x16x32_bf16(af[m], bfr[n], acc[m][n], 0, 0, 0);
        __syncthreads();   // vmcnt(0)+lgkmcnt(0)+barrier: next tile landed
        cur ^= 1;
    }

    // epilogue: frag row = (lane>>4)*4 + j, col = lane&15
    const int ro = (lane >> 4) * 4;
    const int colb = bn * 256 + wn * 64;
    const int rowb = bm * 256 + wm * 128;
    float bv[4];
    if constexpr (HAS_BIAS) {
#pragma unroll
        for (int n = 0; n < 4; n++) bv[n] = bias[colb + n * 16 + r];
    }

    if constexpr (OMODE == 0) {
        float* Cp = (float*)Cv + (size_t)z * sC;
#pragma unroll
        for (int m = 0; m < 8; m++)
#pragma unroll
            for (int n = 0; n < 4; n++) {
                const int col = colb + n * 16 + r;
#pragma unroll
                for (int j = 0; j < 4; j++) {
                    float vv = acc[m][n][j];
                    if constexpr (HAS_BIAS) vv += bv[n];
                    Cp[(size_t)(rowb + m * 16 + ro + j) * ldc + col] = vv;
                }
            }
    } else if constexpr (OMODE == 1) {
        ushort* Cp = (ushort*)Cv + (size_t)z * sC;
#pragma unroll
        for (int m = 0; m < 8; m++)
#pragma unroll
            for (int n = 0; n < 4; n++) {
                const int col = colb + n * 16 + r;
#pragma unroll
                for (int j = 0; j < 4; j++) {
                    float vv = acc[m][n][j];
                    if constexpr (HAS_BIAS) vv += bv[n];
                    Cp[(size_t)(rowb + m * 16 + ro + j) * ldc + col] = f2b(vv);
                }
            }
    } else {
        // transposed bf16 store: Cp[col*ldc + row]; 4 consecutive rows -> ushort4
        ushort* Cp = (ushort*)Cv + (size_t)z * sC;
#pragma unroll
        for (int m = 0; m < 8; m++)
#pragma unroll
            for (int n = 0; n < 4; n++) {
                const int col = colb + n * 16 + r;
                float v0 = acc[m][n][0], v1 = acc[m][n][1], v2 = acc[m][n][2], v3 = acc[m][n][3];
                if constexpr (HAS_BIAS) { v0 += bv[n]; v1 += bv[n]; v2 += bv[n]; v3 += bv[n]; }
                ushort4 u;
                u.x = f2b(v0); u.y = f2b(v1); u.z = f2b(v2); u.w = f2b(v3);
                *(ushort4*)&Cp[(size_t)col * ldc + rowb + m * 16 + ro] = u;
            }
    }
}

// ---------------------------------------------------------------------------
__global__ __launch_bounds__(256) void cast_f32_bf16_k(
    const float* __restrict__ in, ushort* __restrict__ outp, int n)
{
    int idx = (blockIdx.x * 256 + threadIdx.x) * 4;
    if (idx >= n) return;
    float4 f = *(const float4*)&in[idx];
    uint2 u; u.x = pkbf(f.x, f.y); u.y = pkbf(f.z, f.w);
    *(uint2*)&outp[idx] = u;
}

// cast q,k,v -> contiguous bf16 [3][n_each]; blockIdx.y selects the input
__global__ __launch_bounds__(256) void cast3_k(
    const float* __restrict__ q, const float* __restrict__ k,
    const float* __restrict__ v, ushort* __restrict__ outp, int n_each)
{
    const float* src = (blockIdx.y == 0) ? q : (blockIdx.y == 1) ? k : v;
    ushort* dst = outp + (size_t)blockIdx.y * n_each;
    const int stride = gridDim.x * 256 * 4;
    for (int idx = (blockIdx.x * 256 + threadIdx.x) * 4; idx < n_each; idx += stride) {
        float4 f = *(const float4*)&src[idx];
        uint2 u; u.x = pkbf(f.x, f.y); u.y = pkbf(f.z, f.w);
        *(uint2*)&dst[idx] = u;
    }
}

// ---------------------------------------------------------------------------
// In-place masked softmax over each row of w (fp32, row length 2048).
// x = score/32, masked -> -1e9 exactly, then row softmax. bf16 copy -> wb.
// ---------------------------------------------------------------------------
__global__ __launch_bounds__(256) void softmax_rows(
    float* __restrict__ w, const int* __restrict__ mask, ushort* __restrict__ wb)
{
    __shared__ float red[8];
    const int rid = blockIdx.x;            // b*S + q
    const int b = rid >> 11;               // S = 2048
    float* row = w + (size_t)rid * S_LEN;
    ushort* brow = wb + (size_t)rid * S_LEN;
    const int* mrow = mask + (size_t)b * S_LEN;
    const int t = threadIdx.x;
    const int wid = t >> 6, lane = t & 63;
    const float scale = 0.03125f;          // 1/sqrt(1024)

    float x[8];
    float mx = -3.0e38f;
#pragma unroll
    for (int i = 0; i < 2; i++) {
        const int idx = (t + i * 256) * 4;
        float4 s4 = *(const float4*)&row[idx];
        int4 m4 = *(const int4*)&mrow[idx];
        float* xp = &x[i * 4];
        xp[0] = (m4.x == 0) ? -1.0e9f : s4.x * scale;
        xp[1] = (m4.y == 0) ? -1.0e9f : s4.y * scale;
        xp[2] = (m4.z == 0) ? -1.0e9f : s4.z * scale;
        xp[3] = (m4.w == 0) ? -1.0e9f : s4.w * scale;
        mx = fmaxf(mx, fmaxf(fmaxf(xp[0], xp[1]), fmaxf(xp[2], xp[3])));
    }
#pragma unroll
    for (int off = 32; off; off >>= 1) mx = fmaxf(mx, __shfl_xor(mx, off));
    if (lane == 0) red[wid] = mx;
    __syncthreads();
    mx = fmaxf(fmaxf(red[0], red[1]), fmaxf(red[2], red[3]));

    float sum = 0.0f;
#pragma unroll
    for (int i = 0; i < 8; i++) { x[i] = __expf(x[i] - mx); sum += x[i]; }
#pragma unroll
    for (int off = 32; off; off >>= 1) sum += __shfl_xor(sum, off);
    if (lane == 0) red[4 + wid] = sum;
    __syncthreads();
    sum = red[4] + red[5] + red[6] + red[7];
    const float inv = 1.0f / sum;

#pragma unroll
    for (int i = 0; i < 2; i++) {
        const int idx = (t + i * 256) * 4;
        float4 o;
        o.x = x[i * 4 + 0] * inv; o.y = x[i * 4 + 1] * inv;
        o.z = x[i * 4 + 2] * inv; o.w = x[i * 4 + 3] * inv;
        *(float4*)&row[idx] = o;
        uint2 ub;
        ub.x = pkbf(o.x, o.y);
        ub.y = pkbf(o.z, o.w);
        *(uint2*)&brow[idx] = ub;
    }
}

// ---------------------------------------------------------------------------
extern "C" void kernel_launch(void* const* d_in, const int* in_sizes, int n_in,
                              void* d_out, int out_size, void* d_ws, size_t ws_size,
                              hipStream_t stream)
{
    const float* q    = (const float*)d_in[0];
    const float* k    = (const float*)d_in[1];
    const float* v    = (const float*)d_in[2];
    const int*   mask = (const int*)d_in[3];
    const float* Wq   = (const float*)d_in[4];
    const float* bq   = (const float*)d_in[5];
    const float* Wout = (const float*)d_in[6];
    const float* bout = (const float*)d_in[7];

    float* out     = (float*)d_out;                             // [8,2048,1024] fp32
    float* weights = out + (size_t)NBATCH * S_LEN * DM;         // [8,2048,2048] fp32

    const size_t NTOK = (size_t)NBATCH * S_LEN;                 // 16384

    // Overlays of dead d_out regions:
    // 1) bf16 q/k/v casts live in the weights region (134 MB; dead until scores)
    ushort* qkvb = (ushort*)weights;                            // [3][16384*1024] bf16
    ushort* qb = qkvb;
    ushort* kb = qb + NTOK * DM;
    ushort* vb = kb + NTOK * DM;
    // 2) bf16 softmax weights live in the out region (67 MB; dead until outproj)
    ushort* wbf = (ushort*)d_out;

    ushort* qp    = (ushort*)d_ws;                              // [16384,1024] bf16
    ushort* kp    = qp + NTOK * DM;
    ushort* vpT   = kp + NTOK * DM;                             // [8,1024,2048] bf16
    ushort* attn  = qp;                                         // alias: qp dead after scores
    ushort* Wqb   = vpT + NTOK * DM;
    ushort* Woutb = Wqb + (size_t)DM * DM;

    dim3 blk(256, 1, 1);
    dim3 blk5(512, 1, 1);

    cast_f32_bf16_k<<<dim3(1024, 1, 1), blk, 0, stream>>>(Wq, Wqb, DM * DM);
    cast_f32_bf16_k<<<dim3(1024, 1, 1), blk, 0, stream>>>(Wout, Woutb, DM * DM);
    cast3_k<<<dim3(2048, 3, 1), blk, 0, stream>>>(q, k, v, qkvb, (int)(NTOK * DM));

    // q,k projections: [16384,1024] x Wq[1024,1024]^T + bq -> bf16
    gemm256<1, true><<<dim3(64, 4, 1), blk5, 0, stream>>>(
        qb, Wqb, qp, bq, 1024, 1024, 1024, 1024, 0, 0, 0);
    gemm256<1, true><<<dim3(64, 4, 1), blk5, 0, stream>>>(
        kb, Wqb, kp, bq, 1024, 1024, 1024, 1024, 0, 0, 0);
    // v projection, stored transposed per batch: vpT[b][d][s]
    gemm256<2, true><<<dim3(8, 4, NBATCH), blk5, 0, stream>>>(
        vb, Wqb, vpT, bq, 1024, 1024, 1024, 2048,
        (long long)S_LEN * DM, 0, (long long)DM * S_LEN);

    // scores = qp * kp^T -> fp32 weights region of d_out (overwrites qkvb: dead)
    gemm256<0, false><<<dim3(8, 8, NBATCH), blk5, 0, stream>>>(
        qp, kp, weights, nullptr, 1024, 1024, 1024, 2048,
        (long long)S_LEN * DM, (long long)S_LEN * DM, (long long)S_LEN * S_LEN);

    // masked softmax in place (scale 1/32, mask==0 -> -1e9), bf16 copy -> wbf
    softmax_rows<<<dim3(NBATCH * S_LEN, 1, 1), blk, 0, stream>>>(weights, mask, wbf);

    // attn = softmax(weights) * vp   (A = wbf bf16, B = vpT in N x K layout)
    gemm256<1, false><<<dim3(8, 4, NBATCH), blk5, 0, stream>>>(
        wbf, vpT, attn, nullptr, 2048, 2048, 2048, 1024,
        (long long)S_LEN * S_LEN, (long long)DM * S_LEN, (long long)S_LEN * DM);

    // out = attn * Wout^T + bout -> fp32 (overwrites the wbf overlay)
    gemm256<0, true><<<dim3(64, 4, 1), blk5, 0, stream>>>(
        attn, Woutb, out, bout, 1024, 1024, 1024, 1024, 0, 0, 0);
}

// Round 5
// 472.237 us; speedup vs baseline: 1.3455x; 1.1207x over previous
//
#include <hip/hip_runtime.h>
#include <hip/hip_bf16.h>

typedef __attribute__((ext_vector_type(8))) short short8;
typedef __attribute__((ext_vector_type(4))) float f32x4;

#define S_LEN 2048
#define DM 1024
#define NBATCH 8

__device__ __forceinline__ ushort f2b(float f) {
    union { float f; unsigned u; } a; a.f = f;
    unsigned u = a.u;
    u += 0x7fffu + ((u >> 16) & 1u);   // round-to-nearest-even
    return (ushort)(u >> 16);
}

// packed f32 pair -> bf16x2 (compiler emits v_cvt_pk_bf16_f32)
__device__ __forceinline__ unsigned pkbf(float a, float b) {
    float2 t; t.x = a; t.y = b;
    __hip_bfloat162 h = __float22bfloat162_rn(t);
    union { __hip_bfloat162 h; unsigned u; } c; c.h = h;
    return c.u;
}

#define GLDS(gp, lp) __builtin_amdgcn_global_load_lds( \
    (const __attribute__((address_space(1))) void*)(gp), \
    (__attribute__((address_space(3))) void*)(lp), 16, 0, 0)

// ---------------------------------------------------------------------------
// 256x256 MFMA GEMM, BK=64, 8 waves (2M x 4N), per-wave 128x64 output.
// C[M,N] = A[M,K] * B[N,K]^T (+ bias[N]); A,B bf16.
// Schedule: full next-K-tile prefetch issued at TOP of current tile's compute
// (4 quadrant phases x 16 MFMA, setprio-wrapped), one __syncthreads per tile.
// vmcnt(0) drain at the barrier is ~free: loads got ~4 MFMA-phases of cover.
// LDS [256][64] bf16 rows = 128 B; XOR swizzle byte ^= ((row&7)<<4):
// write-linear via pre-swizzled global source (rule #21), read-swizzled.
// 16-lane groups then cover all 32 banks 2-way = conflict-free (m136).
// OMODE: 0 = fp32 C, 1 = bf16 C, 2 = bf16 C transposed (C[col*ldc+row]).
// ---------------------------------------------------------------------------
template<int OMODE, bool HAS_BIAS>
__global__ __launch_bounds__(512, 2) void gemm256(
    const ushort* __restrict__ A, const ushort* __restrict__ B,
    void* __restrict__ Cv, const float* __restrict__ bias,
    int K, int lda, int ldb, int ldc,
    long long sA, long long sB, long long sC)
{
    __shared__ __align__(16) ushort lA[2][256 * 64];   // 2 x 32 KB
    __shared__ __align__(16) ushort lB[2][256 * 64];   // 2 x 32 KB

    const int t = threadIdx.x;
    const int lane = t & 63;
    const int wid = t >> 6;
    const int wm = wid >> 2, wn = wid & 3;             // 2 x 4 wave grid
    const int z = blockIdx.z;

    // --- XCD-aware bijective swizzle (m204), bn-fastest within XCD chunk ---
    const int gx = gridDim.x, gy = gridDim.y;
    const int nwg = gx * gy;
    const int lid = blockIdx.y * gx + blockIdx.x;
    const int qq = nwg >> 3, r8 = nwg & 7;
    const int xcd = lid & 7, off = lid >> 3;
    const int w = (xcd < r8 ? xcd * (qq + 1) : r8 * (qq + 1) + (xcd - r8) * qq) + off;
    const int bm = w / gy, bn = w % gy;

    const ushort* Ap = A + (size_t)z * sA + (size_t)(bm * 256) * lda;
    const ushort* Bp = B + (size_t)z * sB + (size_t)(bn * 256) * ldb;

    f32x4 acc[8][4] = {};

    // staging map per 8-KB GLDS issue: 64 rows x 128 B; 4 issues per operand
    const int srow = t >> 3;                               // 0..63
    const int scol = (((t & 7) ^ (srow & 7))) * 8;         // pre-swizzled col (elems)
    const int nK = K >> 6;

    // read map
    const int r = lane & 15;
    const int swz = (r & 7) << 4;                          // byte XOR for this lane

    // ---- stage one full K-tile (A+B, 8 GLDS) into buffer `buf` ----
    auto stage = [&](int kt, int buf) {
        const int k0 = kt * 64;
        const ushort* ga = Ap + (size_t)srow * lda + k0 + scol;
        char* dA = (char*)lA[buf];
#pragma unroll
        for (int i = 0; i < 4; i++)
            GLDS(ga + (size_t)(64 * i) * lda, dA + i * 8192 + t * 16);
        const ushort* gb = Bp + (size_t)srow * ldb + k0 + scol;
        char* dB = (char*)lB[buf];
#pragma unroll
        for (int i = 0; i < 4; i++)
            GLDS(gb + (size_t)(64 * i) * ldb, dB + i * 8192 + t * 16);
    };

    stage(0, 0);
    __syncthreads();

    int cur = 0;
    for (int kt = 0; kt < nK; ++kt) {
        if (kt + 1 < nK) stage(kt + 1, cur ^ 1);   // issue early: flies under compute
        const char* la = (const char*)lA[cur];
        const char* lb = (const char*)lB[cur];
#pragma unroll
        for (int mh = 0; mh < 2; mh++) {
            short8 af[4][2];
#pragma unroll
            for (int m = 0; m < 4; m++) {
                const int row = wm * 128 + mh * 64 + m * 16 + r;
#pragma unroll
                for (int ks = 0; ks < 2; ks++)
                    af[m][ks] = *(const short8*)(la + row * 128 + ((ks * 64 + (lane >> 4) * 16) ^ swz));
            }
#pragma unroll
            for (int nh = 0; nh < 2; nh++) {
                short8 bf[2][2];
#pragma unroll
                for (int n = 0; n < 2; n++) {
                    const int row = wn * 64 + nh * 32 + n * 16 + r;
#pragma unroll
                    for (int ks = 0; ks < 2; ks++)
                        bf[n][ks] = *(const short8*)(lb + row * 128 + ((ks * 64 + (lane >> 4) * 16) ^ swz));
                }
                __builtin_amdgcn_s_setprio(1);
#pragma unroll
                for (int m = 0; m < 4; m++)
#pragma unroll
                    for (int n = 0; n < 2; n++)
#pragma unroll
                        for (int ks = 0; ks < 2; ks++)
                            acc[mh * 4 + m][nh * 2 + n] = __builtin_amdgcn_mfma_f32_16x16x32_bf16(
                                af[m][ks], bf[n][ks], acc[mh * 4 + m][nh * 2 + n], 0, 0, 0);
                __builtin_amdgcn_s_setprio(0);
            }
        }
        __syncthreads();   // vmcnt(0)+lgkmcnt(0)+barrier: next tile landed, reads done
        cur ^= 1;
    }

    // epilogue: frag row = (lane>>4)*4 + j, col = lane&15
    const int ro = (lane >> 4) * 4;
    const int colb = bn * 256 + wn * 64;
    const int rowb = bm * 256 + wm * 128;
    float bv[4];
    if constexpr (HAS_BIAS) {
#pragma unroll
        for (int n = 0; n < 4; n++) bv[n] = bias[colb + n * 16 + r];
    }

    if constexpr (OMODE == 0) {
        float* Cp = (float*)Cv + (size_t)z * sC;
#pragma unroll
        for (int m = 0; m < 8; m++)
#pragma unroll
            for (int n = 0; n < 4; n++) {
                const int col = colb + n * 16 + r;
#pragma unroll
                for (int j = 0; j < 4; j++) {
                    float vv = acc[m][n][j];
                    if constexpr (HAS_BIAS) vv += bv[n];
                    Cp[(size_t)(rowb + m * 16 + ro + j) * ldc + col] = vv;
                }
            }
    } else if constexpr (OMODE == 1) {
        ushort* Cp = (ushort*)Cv + (size_t)z * sC;
#pragma unroll
        for (int m = 0; m < 8; m++)
#pragma unroll
            for (int n = 0; n < 4; n++) {
                const int col = colb + n * 16 + r;
#pragma unroll
                for (int j = 0; j < 4; j++) {
                    float vv = acc[m][n][j];
                    if constexpr (HAS_BIAS) vv += bv[n];
                    Cp[(size_t)(rowb + m * 16 + ro + j) * ldc + col] = f2b(vv);
                }
            }
    } else {
        // transposed bf16 store: Cp[col*ldc + row]; 4 consecutive rows -> ushort4
        ushort* Cp = (ushort*)Cv + (size_t)z * sC;
#pragma unroll
        for (int m = 0; m < 8; m++)
#pragma unroll
            for (int n = 0; n < 4; n++) {
                const int col = colb + n * 16 + r;
                float v0 = acc[m][n][0], v1 = acc[m][n][1], v2 = acc[m][n][2], v3 = acc[m][n][3];
                if constexpr (HAS_BIAS) { v0 += bv[n]; v1 += bv[n]; v2 += bv[n]; v3 += bv[n]; }
                ushort4 u;
                u.x = f2b(v0); u.y = f2b(v1); u.z = f2b(v2); u.w = f2b(v3);
                *(ushort4*)&Cp[(size_t)col * ldc + rowb + m * 16 + ro] = u;
            }
    }
}

// ---------------------------------------------------------------------------
__global__ __launch_bounds__(256) void cast_f32_bf16_k(
    const float* __restrict__ in, ushort* __restrict__ outp, int n)
{
    int idx = (blockIdx.x * 256 + threadIdx.x) * 4;
    if (idx >= n) return;
    float4 f = *(const float4*)&in[idx];
    uint2 u; u.x = pkbf(f.x, f.y); u.y = pkbf(f.z, f.w);
    *(uint2*)&outp[idx] = u;
}

// cast q,k,v -> contiguous bf16 [3][n_each]; blockIdx.y selects the input
__global__ __launch_bounds__(256) void cast3_k(
    const float* __restrict__ q, const float* __restrict__ k,
    const float* __restrict__ v, ushort* __restrict__ outp, int n_each)
{
    const float* src = (blockIdx.y == 0) ? q : (blockIdx.y == 1) ? k : v;
    ushort* dst = outp + (size_t)blockIdx.y * n_each;
    const int stride = gridDim.x * 256 * 4;
    for (int idx = (blockIdx.x * 256 + threadIdx.x) * 4; idx < n_each; idx += stride) {
        float4 f = *(const float4*)&src[idx];
        uint2 u; u.x = pkbf(f.x, f.y); u.y = pkbf(f.z, f.w);
        *(uint2*)&dst[idx] = u;
    }
}

// ---------------------------------------------------------------------------
// In-place masked softmax over each row of w (fp32, row length 2048).
// x = score/32, masked -> -1e9 exactly, then row softmax. bf16 copy -> wb.
// ---------------------------------------------------------------------------
__global__ __launch_bounds__(256) void softmax_rows(
    float* __restrict__ w, const int* __restrict__ mask, ushort* __restrict__ wb)
{
    __shared__ float red[8];
    const int rid = blockIdx.x;            // b*S + q
    const int b = rid >> 11;               // S = 2048
    float* row = w + (size_t)rid * S_LEN;
    ushort* brow = wb + (size_t)rid * S_LEN;
    const int* mrow = mask + (size_t)b * S_LEN;
    const int t = threadIdx.x;
    const int wid = t >> 6, lane = t & 63;
    const float scale = 0.03125f;          // 1/sqrt(1024)

    float x[8];
    float mx = -3.0e38f;
#pragma unroll
    for (int i = 0; i < 2; i++) {
        const int idx = (t + i * 256) * 4;
        float4 s4 = *(const float4*)&row[idx];
        int4 m4 = *(const int4*)&mrow[idx];
        float* xp = &x[i * 4];
        xp[0] = (m4.x == 0) ? -1.0e9f : s4.x * scale;
        xp[1] = (m4.y == 0) ? -1.0e9f : s4.y * scale;
        xp[2] = (m4.z == 0) ? -1.0e9f : s4.z * scale;
        xp[3] = (m4.w == 0) ? -1.0e9f : s4.w * scale;
        mx = fmaxf(mx, fmaxf(fmaxf(xp[0], xp[1]), fmaxf(xp[2], xp[3])));
    }
#pragma unroll
    for (int off = 32; off; off >>= 1) mx = fmaxf(mx, __shfl_xor(mx, off));
    if (lane == 0) red[wid] = mx;
    __syncthreads();
    mx = fmaxf(fmaxf(red[0], red[1]), fmaxf(red[2], red[3]));

    float sum = 0.0f;
#pragma unroll
    for (int i = 0; i < 8; i++) { x[i] = __expf(x[i] - mx); sum += x[i]; }
#pragma unroll
    for (int off = 32; off; off >>= 1) sum += __shfl_xor(sum, off);
    if (lane == 0) red[4 + wid] = sum;
    __syncthreads();
    sum = red[4] + red[5] + red[6] + red[7];
    const float inv = 1.0f / sum;

#pragma unroll
    for (int i = 0; i < 2; i++) {
        const int idx = (t + i * 256) * 4;
        float4 o;
        o.x = x[i * 4 + 0] * inv; o.y = x[i * 4 + 1] * inv;
        o.z = x[i * 4 + 2] * inv; o.w = x[i * 4 + 3] * inv;
        *(float4*)&row[idx] = o;
        uint2 ub;
        ub.x = pkbf(o.x, o.y);
        ub.y = pkbf(o.z, o.w);
        *(uint2*)&brow[idx] = ub;
    }
}

// ---------------------------------------------------------------------------
extern "C" void kernel_launch(void* const* d_in, const int* in_sizes, int n_in,
                              void* d_out, int out_size, void* d_ws, size_t ws_size,
                              hipStream_t stream)
{
    const float* q    = (const float*)d_in[0];
    const float* k    = (const float*)d_in[1];
    const float* v    = (const float*)d_in[2];
    const int*   mask = (const int*)d_in[3];
    const float* Wq   = (const float*)d_in[4];
    const float* bq   = (const float*)d_in[5];
    const float* Wout = (const float*)d_in[6];
    const float* bout = (const float*)d_in[7];

    float* out     = (float*)d_out;                             // [8,2048,1024] fp32
    float* weights = out + (size_t)NBATCH * S_LEN * DM;         // [8,2048,2048] fp32

    const size_t NTOK = (size_t)NBATCH * S_LEN;                 // 16384

    // Overlays of dead d_out regions:
    // 1) bf16 q/k/v casts live in the weights region (134 MB; dead until scores)
    ushort* qkvb = (ushort*)weights;                            // [3][16384*1024] bf16
    ushort* qb = qkvb;
    ushort* kb = qb + NTOK * DM;
    ushort* vb = kb + NTOK * DM;
    // 2) bf16 softmax weights live in the out region (67 MB; dead until outproj)
    ushort* wbf = (ushort*)d_out;

    ushort* qp    = (ushort*)d_ws;                              // [16384,1024] bf16
    ushort* kp    = qp + NTOK * DM;
    ushort* vpT   = kp + NTOK * DM;                             // [8,1024,2048] bf16
    ushort* attn  = qp;                                         // alias: qp dead after scores
    ushort* Wqb   = vpT + NTOK * DM;
    ushort* Woutb = Wqb + (size_t)DM * DM;

    dim3 blk(256, 1, 1);
    dim3 blk5(512, 1, 1);

    cast_f32_bf16_k<<<dim3(1024, 1, 1), blk, 0, stream>>>(Wq, Wqb, DM * DM);
    cast_f32_bf16_k<<<dim3(1024, 1, 1), blk, 0, stream>>>(Wout, Woutb, DM * DM);
    cast3_k<<<dim3(2048, 3, 1), blk, 0, stream>>>(q, k, v, qkvb, (int)(NTOK * DM));

    // q,k projections: [16384,1024] x Wq[1024,1024]^T + bq -> bf16
    gemm256<1, true><<<dim3(64, 4, 1), blk5, 0, stream>>>(
        qb, Wqb, qp, bq, 1024, 1024, 1024, 1024, 0, 0, 0);
    gemm256<1, true><<<dim3(64, 4, 1), blk5, 0, stream>>>(
        kb, Wqb, kp, bq, 1024, 1024, 1024, 1024, 0, 0, 0);
    // v projection, stored transposed per batch: vpT[b][d][s]
    gemm256<2, true><<<dim3(8, 4, NBATCH), blk5, 0, stream>>>(
        vb, Wqb, vpT, bq, 1024, 1024, 1024, 2048,
        (long long)S_LEN * DM, 0, (long long)DM * S_LEN);

    // scores = qp * kp^T -> fp32 weights region of d_out (overwrites qkvb: dead)
    gemm256<0, false><<<dim3(8, 8, NBATCH), blk5, 0, stream>>>(
        qp, kp, weights, nullptr, 1024, 1024, 1024, 2048,
        (long long)S_LEN * DM, (long long)S_LEN * DM, (long long)S_LEN * S_LEN);

    // masked softmax in place (scale 1/32, mask==0 -> -1e9), bf16 copy -> wbf
    softmax_rows<<<dim3(NBATCH * S_LEN, 1, 1), blk, 0, stream>>>(weights, mask, wbf);

    // attn = softmax(weights) * vp   (A = wbf bf16, B = vpT in N x K layout)
    gemm256<1, false><<<dim3(8, 4, NBATCH), blk5, 0, stream>>>(
        wbf, vpT, attn, nullptr, 2048, 2048, 2048, 1024,
        (long long)S_LEN * S_LEN, (long long)DM * S_LEN, (long long)S_LEN * DM);

    // out = attn * Wout^T + bout -> fp32 (overwrites the wbf overlay)
    gemm256<0, true><<<dim3(64, 4, 1), blk5, 0, stream>>>(
        attn, Woutb, out, bout, 1024, 1024, 1024, 1024, 0, 0, 0);
}

// Round 6
// 458.026 us; speedup vs baseline: 1.3873x; 1.0310x over previous
//
#include <hip/hip_runtime.h>
#include <hip/hip_bf16.h>

typedef __attribute__((ext_vector_type(8))) short short8;
typedef __attribute__((ext_vector_type(4))) float f32x4;

#define S_LEN 2048
#define DM 1024
#define NBATCH 8

__device__ __forceinline__ ushort f2b(float f) {
    union { float f; unsigned u; } a; a.f = f;
    unsigned u = a.u;
    u += 0x7fffu + ((u >> 16) & 1u);   // round-to-nearest-even
    return (ushort)(u >> 16);
}

// packed f32 pair -> bf16x2 (compiler emits v_cvt_pk_bf16_f32)
__device__ __forceinline__ unsigned pkbf(float a, float b) {
    float2 t; t.x = a; t.y = b;
    __hip_bfloat162 h = __float22bfloat162_rn(t);
    union { __hip_bfloat162 h; unsigned u; } c; c.h = h;
    return c.u;
}

#define GLDS(gp, lp) __builtin_amdgcn_global_load_lds( \
    (const __attribute__((address_space(1))) void*)(gp), \
    (__attribute__((address_space(3))) void*)(lp), 16, 0, 0)

#define BAR() __builtin_amdgcn_s_barrier()
#define VMW(N) asm volatile("s_waitcnt vmcnt(" #N ")" ::: "memory")

// one quadrant: 16 MFMA, setprio-wrapped (T5). MH/NH must be literals.
#define QUAD(AF, BF, MH, NH) do {                                              \
    __builtin_amdgcn_s_setprio(1);                                             \
    _Pragma("unroll") for (int m_ = 0; m_ < 4; m_++)                           \
    _Pragma("unroll") for (int n_ = 0; n_ < 2; n_++)                           \
    _Pragma("unroll") for (int ks_ = 0; ks_ < 2; ks_++)                        \
        acc[(MH)*4 + m_][(NH)*2 + n_] = __builtin_amdgcn_mfma_f32_16x16x32_bf16( \
            AF[m_][ks_], BF[n_][ks_], acc[(MH)*4 + m_][(NH)*2 + n_], 0, 0, 0); \
    __builtin_amdgcn_s_setprio(0);                                             \
} while (0)

// ---------------------------------------------------------------------------
// 256x256 MFMA GEMM, BK=64, 8 waves (2M x 4N), per-wave 128x64 output.
// C[M,N] = A[M,K] * B[N,K]^T (+ bias[N]); A,B bf16.
// m201-style 4-phase/K-tile schedule, half-tile (128row x 64col) staging:
//   ph0: ds_read af(mh0)+b0 | stage (t+1).A1 | bar | MFMA q(0,0) | bar
//   ph1: ds_read b1         | stage (t+1).B1 | bar | MFMA q(0,1) | bar
//   ph2: ds_read af(mh1)    | stage (t+2).B0 | bar | MFMA q(1,0) | bar
//   ph3:                      stage (t+2).A0 | bar | MFMA q(1,1) | bar
//   boundary: vmcnt(4) (vmcnt(0) only entering the last tile) + bar
// Each LDS region ds_read exactly once/tile into regs -> fixed death phases:
// A-half dies ph2, B-half ph1 -> the t+2 stages above target dead regions.
// FIFO: boundary outstanding = 12 loads, oldest 8 = next tile's 4 halves.
// LDS rows 128 B, XOR swizzle byte ^= ((row&7)<<4), write-linear via
// pre-swizzled global source (rule #21), read-swizzled.
// OMODE: 0 = fp32 C, 1 = bf16 C, 2 = bf16 C transposed (C[col*ldc+row]).
// ---------------------------------------------------------------------------
template<int OMODE, bool HAS_BIAS>
__global__ __launch_bounds__(512, 2) void gemm256(
    const ushort* __restrict__ A, const ushort* __restrict__ B,
    void* __restrict__ Cv, const float* __restrict__ bias,
    int K, int lda, int ldb, int ldc,
    long long sA, long long sB, long long sC)
{
    __shared__ __align__(16) ushort lA[2][2][128 * 64];   // [buf][half] 64 KB
    __shared__ __align__(16) ushort lB[2][2][128 * 64];   // 64 KB

    const int t = threadIdx.x;
    const int lane = t & 63;
    const int wid = t >> 6;
    const int wm = wid >> 2, wn = wid & 3;                // 2 x 4 wave grid
    const int z = blockIdx.z;

    // --- XCD-aware bijective swizzle (m204), bn-fastest within XCD chunk ---
    const int gx = gridDim.x, gy = gridDim.y;
    const int nwg = gx * gy;
    const int lid = blockIdx.y * gx + blockIdx.x;
    const int qq = nwg >> 3, r8 = nwg & 7;
    const int xcd = lid & 7, off = lid >> 3;
    const int w = (xcd < r8 ? xcd * (qq + 1) : r8 * (qq + 1) + (xcd - r8) * qq) + off;
    const int bm = w / gy, bn = w % gy;

    const ushort* Ap = A + (size_t)z * sA + (size_t)(bm * 256) * lda;
    const ushort* Bp = B + (size_t)z * sB + (size_t)(bn * 256) * ldb;

    f32x4 acc[8][4] = {};

    // staging map: half-tile = 128 rows x 128 B; 2 GLDS issues (64 rows each)
    const int srow = t >> 3;                               // 0..63
    const int scol = ((t & 7) ^ (srow & 7)) * 8;           // pre-swizzled col

    auto stA = [&](int kt, int h, int buf) {
        const ushort* g = Ap + (size_t)(h * 128 + srow) * lda + kt * 64 + scol;
        char* d = (char*)lA[buf][h];
        GLDS(g, d + t * 16);
        GLDS(g + (size_t)64 * lda, d + 8192 + t * 16);
    };
    auto stB = [&](int kt, int h, int buf) {
        const ushort* g = Bp + (size_t)(h * 128 + srow) * ldb + kt * 64 + scol;
        char* d = (char*)lB[buf][h];
        GLDS(g, d + t * 16);
        GLDS(g + (size_t)64 * ldb, d + 8192 + t * 16);
    };

    const int nK = K >> 6;

    // prologue: tile0 complete (8 loads) + tile1 A0,B0 (4 loads)
    stA(0, 0, 0); stB(0, 0, 0); stA(0, 1, 0); stB(0, 1, 0);
    if (nK > 1) {
        stA(1, 0, 1); stB(1, 0, 1);
        VMW(4);
    } else {
        VMW(0);
    }
    BAR();

    // read map
    const int r = lane & 15;
    const int swz = (r & 7) << 4;
    const int cb0 = ((lane >> 4) * 16) ^ swz;
    const int cb1 = (64 + (lane >> 4) * 16) ^ swz;
    const int lbr = (wn & 1) * 64;                         // local row base in B half
    const int bh = wn >> 1;                                // B half index

    int cur = 0;
    for (int kt = 0; kt < nK; ++kt) {
        const char* la = (const char*)lA[cur][wm];
        const char* lb = (const char*)lB[cur][bh];
        short8 af[4][2], b0f[2][2], b1f[2][2];

        // ---- phase 0 ----
#pragma unroll
        for (int m = 0; m < 4; m++) {
            const int lr = m * 16 + r;
            af[m][0] = *(const short8*)(la + lr * 128 + cb0);
            af[m][1] = *(const short8*)(la + lr * 128 + cb1);
        }
#pragma unroll
        for (int n = 0; n < 2; n++) {
            const int lr = lbr + n * 16 + r;
            b0f[n][0] = *(const short8*)(lb + lr * 128 + cb0);
            b0f[n][1] = *(const short8*)(lb + lr * 128 + cb1);
        }
        if (kt + 1 < nK) stA(kt + 1, 1, cur ^ 1);
        BAR();
        QUAD(af, b0f, 0, 0);
        BAR();

        // ---- phase 1 ----
#pragma unroll
        for (int n = 0; n < 2; n++) {
            const int lr = lbr + 32 + n * 16 + r;
            b1f[n][0] = *(const short8*)(lb + lr * 128 + cb0);
            b1f[n][1] = *(const short8*)(lb + lr * 128 + cb1);
        }
        if (kt + 1 < nK) stB(kt + 1, 1, cur ^ 1);
        BAR();
        QUAD(af, b1f, 0, 1);
        BAR();

        // ---- phase 2 ----
#pragma unroll
        for (int m = 0; m < 4; m++) {
            const int lr = 64 + m * 16 + r;
            af[m][0] = *(const short8*)(la + lr * 128 + cb0);
            af[m][1] = *(const short8*)(la + lr * 128 + cb1);
        }
        if (kt + 2 < nK) stB(kt + 2, 0, cur);
        BAR();
        QUAD(af, b0f, 1, 0);
        BAR();

        // ---- phase 3 ----
        if (kt + 2 < nK) stA(kt + 2, 0, cur);
        BAR();
        QUAD(af, b1f, 1, 1);
        BAR();

        // ---- K-tile boundary: counted wait (T4), never 0 mid-loop ----
        if (kt + 1 < nK) {
            if (kt + 1 == nK - 1) { VMW(0); } else { VMW(4); }
            BAR();
        }
        cur ^= 1;
    }

    // epilogue: frag row = (lane>>4)*4 + j, col = lane&15
    const int ro = (lane >> 4) * 4;
    const int colb = bn * 256 + wn * 64;
    const int rowb = bm * 256 + wm * 128;
    float bv[4];
    if constexpr (HAS_BIAS) {
#pragma unroll
        for (int n = 0; n < 4; n++) bv[n] = bias[colb + n * 16 + r];
    }

    if constexpr (OMODE == 0) {
        float* Cp = (float*)Cv + (size_t)z * sC;
#pragma unroll
        for (int m = 0; m < 8; m++)
#pragma unroll
            for (int n = 0; n < 4; n++) {
                const int col = colb + n * 16 + r;
#pragma unroll
                for (int j = 0; j < 4; j++) {
                    float vv = acc[m][n][j];
                    if constexpr (HAS_BIAS) vv += bv[n];
                    Cp[(size_t)(rowb + m * 16 + ro + j) * ldc + col] = vv;
                }
            }
    } else if constexpr (OMODE == 1) {
        ushort* Cp = (ushort*)Cv + (size_t)z * sC;
#pragma unroll
        for (int m = 0; m < 8; m++)
#pragma unroll
            for (int n = 0; n < 4; n++) {
                const int col = colb + n * 16 + r;
#pragma unroll
                for (int j = 0; j < 4; j++) {
                    float vv = acc[m][n][j];
                    if constexpr (HAS_BIAS) vv += bv[n];
                    Cp[(size_t)(rowb + m * 16 + ro + j) * ldc + col] = f2b(vv);
                }
            }
    } else {
        // transposed bf16 store: Cp[col*ldc + row]; 4 consecutive rows -> ushort4
        ushort* Cp = (ushort*)Cv + (size_t)z * sC;
#pragma unroll
        for (int m = 0; m < 8; m++)
#pragma unroll
            for (int n = 0; n < 4; n++) {
                const int col = colb + n * 16 + r;
                float v0 = acc[m][n][0], v1 = acc[m][n][1], v2 = acc[m][n][2], v3 = acc[m][n][3];
                if constexpr (HAS_BIAS) { v0 += bv[n]; v1 += bv[n]; v2 += bv[n]; v3 += bv[n]; }
                ushort4 u;
                u.x = f2b(v0); u.y = f2b(v1); u.z = f2b(v2); u.w = f2b(v3);
                *(ushort4*)&Cp[(size_t)col * ldc + rowb + m * 16 + ro] = u;
            }
    }
}

// ---------------------------------------------------------------------------
__global__ __launch_bounds__(256) void cast_f32_bf16_k(
    const float* __restrict__ in, ushort* __restrict__ outp, int n)
{
    int idx = (blockIdx.x * 256 + threadIdx.x) * 4;
    if (idx >= n) return;
    float4 f = *(const float4*)&in[idx];
    uint2 u; u.x = pkbf(f.x, f.y); u.y = pkbf(f.z, f.w);
    *(uint2*)&outp[idx] = u;
}

// cast q,k,v -> contiguous bf16 [3][n_each]; blockIdx.y selects the input
__global__ __launch_bounds__(256) void cast3_k(
    const float* __restrict__ q, const float* __restrict__ k,
    const float* __restrict__ v, ushort* __restrict__ outp, int n_each)
{
    const float* src = (blockIdx.y == 0) ? q : (blockIdx.y == 1) ? k : v;
    ushort* dst = outp + (size_t)blockIdx.y * n_each;
    const int stride = gridDim.x * 256 * 4;
    for (int idx = (blockIdx.x * 256 + threadIdx.x) * 4; idx < n_each; idx += stride) {
        float4 f = *(const float4*)&src[idx];
        uint2 u; u.x = pkbf(f.x, f.y); u.y = pkbf(f.z, f.w);
        *(uint2*)&dst[idx] = u;
    }
}

// ---------------------------------------------------------------------------
// In-place masked softmax over each row of w (fp32, row length 2048).
// x = score/32, masked -> -1e9 exactly, then row softmax. bf16 copy -> wb.
// ---------------------------------------------------------------------------
__global__ __launch_bounds__(256) void softmax_rows(
    float* __restrict__ w, const int* __restrict__ mask, ushort* __restrict__ wb)
{
    __shared__ float red[8];
    const int rid = blockIdx.x;            // b*S + q
    const int b = rid >> 11;               // S = 2048
    float* row = w + (size_t)rid * S_LEN;
    ushort* brow = wb + (size_t)rid * S_LEN;
    const int* mrow = mask + (size_t)b * S_LEN;
    const int t = threadIdx.x;
    const int wid = t >> 6, lane = t & 63;
    const float scale = 0.03125f;          // 1/sqrt(1024)

    float x[8];
    float mx = -3.0e38f;
#pragma unroll
    for (int i = 0; i < 2; i++) {
        const int idx = (t + i * 256) * 4;
        float4 s4 = *(const float4*)&row[idx];
        int4 m4 = *(const int4*)&mrow[idx];
        float* xp = &x[i * 4];
        xp[0] = (m4.x == 0) ? -1.0e9f : s4.x * scale;
        xp[1] = (m4.y == 0) ? -1.0e9f : s4.y * scale;
        xp[2] = (m4.z == 0) ? -1.0e9f : s4.z * scale;
        xp[3] = (m4.w == 0) ? -1.0e9f : s4.w * scale;
        mx = fmaxf(mx, fmaxf(fmaxf(xp[0], xp[1]), fmaxf(xp[2], xp[3])));
    }
#pragma unroll
    for (int off = 32; off; off >>= 1) mx = fmaxf(mx, __shfl_xor(mx, off));
    if (lane == 0) red[wid] = mx;
    __syncthreads();
    mx = fmaxf(fmaxf(red[0], red[1]), fmaxf(red[2], red[3]));

    float sum = 0.0f;
#pragma unroll
    for (int i = 0; i < 8; i++) { x[i] = __expf(x[i] - mx); sum += x[i]; }
#pragma unroll
    for (int off = 32; off; off >>= 1) sum += __shfl_xor(sum, off);
    if (lane == 0) red[4 + wid] = sum;
    __syncthreads();
    sum = red[4] + red[5] + red[6] + red[7];
    const float inv = 1.0f / sum;

#pragma unroll
    for (int i = 0; i < 2; i++) {
        const int idx = (t + i * 256) * 4;
        float4 o;
        o.x = x[i * 4 + 0] * inv; o.y = x[i * 4 + 1] * inv;
        o.z = x[i * 4 + 2] * inv; o.w = x[i * 4 + 3] * inv;
        *(float4*)&row[idx] = o;
        uint2 ub;
        ub.x = pkbf(o.x, o.y);
        ub.y = pkbf(o.z, o.w);
        *(uint2*)&brow[idx] = ub;
    }
}

// ---------------------------------------------------------------------------
extern "C" void kernel_launch(void* const* d_in, const int* in_sizes, int n_in,
                              void* d_out, int out_size, void* d_ws, size_t ws_size,
                              hipStream_t stream)
{
    const float* q    = (const float*)d_in[0];
    const float* k    = (const float*)d_in[1];
    const float* v    = (const float*)d_in[2];
    const int*   mask = (const int*)d_in[3];
    const float* Wq   = (const float*)d_in[4];
    const float* bq   = (const float*)d_in[5];
    const float* Wout = (const float*)d_in[6];
    const float* bout = (const float*)d_in[7];

    float* out     = (float*)d_out;                             // [8,2048,1024] fp32
    float* weights = out + (size_t)NBATCH * S_LEN * DM;         // [8,2048,2048] fp32

    const size_t NTOK = (size_t)NBATCH * S_LEN;                 // 16384

    // Overlays of dead d_out regions:
    // 1) bf16 q/k/v casts live in the weights region (134 MB; dead until scores)
    ushort* qkvb = (ushort*)weights;                            // [3][16384*1024] bf16
    ushort* qb = qkvb;
    ushort* kb = qb + NTOK * DM;
    ushort* vb = kb + NTOK * DM;
    // 2) bf16 softmax weights live in the out region (67 MB; dead until outproj)
    ushort* wbf = (ushort*)d_out;

    ushort* qp    = (ushort*)d_ws;                              // [16384,1024] bf16
    ushort* kp    = qp + NTOK * DM;
    ushort* vpT   = kp + NTOK * DM;                             // [8,1024,2048] bf16
    ushort* attn  = qp;                                         // alias: qp dead after scores
    ushort* Wqb   = vpT + NTOK * DM;
    ushort* Woutb = Wqb + (size_t)DM * DM;

    dim3 blk(256, 1, 1);
    dim3 blk5(512, 1, 1);

    cast_f32_bf16_k<<<dim3(1024, 1, 1), blk, 0, stream>>>(Wq, Wqb, DM * DM);
    cast_f32_bf16_k<<<dim3(1024, 1, 1), blk, 0, stream>>>(Wout, Woutb, DM * DM);
    cast3_k<<<dim3(2048, 3, 1), blk, 0, stream>>>(q, k, v, qkvb, (int)(NTOK * DM));

    // q,k projections: [16384,1024] x Wq[1024,1024]^T + bq -> bf16
    gemm256<1, true><<<dim3(64, 4, 1), blk5, 0, stream>>>(
        qb, Wqb, qp, bq, 1024, 1024, 1024, 1024, 0, 0, 0);
    gemm256<1, true><<<dim3(64, 4, 1), blk5, 0, stream>>>(
        kb, Wqb, kp, bq, 1024, 1024, 1024, 1024, 0, 0, 0);
    // v projection, stored transposed per batch: vpT[b][d][s]
    gemm256<2, true><<<dim3(8, 4, NBATCH), blk5, 0, stream>>>(
        vb, Wqb, vpT, bq, 1024, 1024, 1024, 2048,
        (long long)S_LEN * DM, 0, (long long)DM * S_LEN);

    // scores = qp * kp^T -> fp32 weights region of d_out (overwrites qkvb: dead)
    gemm256<0, false><<<dim3(8, 8, NBATCH), blk5, 0, stream>>>(
        qp, kp, weights, nullptr, 1024, 1024, 1024, 2048,
        (long long)S_LEN * DM, (long long)S_LEN * DM, (long long)S_LEN * S_LEN);

    // masked softmax in place (scale 1/32, mask==0 -> -1e9), bf16 copy -> wbf
    softmax_rows<<<dim3(NBATCH * S_LEN, 1, 1), blk, 0, stream>>>(weights, mask, wbf);

    // attn = softmax(weights) * vp   (A = wbf bf16, B = vpT in N x K layout)
    gemm256<1, false><<<dim3(8, 4, NBATCH), blk5, 0, stream>>>(
        wbf, vpT, attn, nullptr, 2048, 2048, 2048, 1024,
        (long long)S_LEN * S_LEN, (long long)DM * S_LEN, (long long)S_LEN * DM);

    // out = attn * Wout^T + bout -> fp32 (overwrites the wbf overlay)
    gemm256<0, true><<<dim3(64, 4, 1), blk5, 0, stream>>>(
        attn, Woutb, out, bout, 1024, 1024, 1024, 1024, 0, 0, 0);
}

// Round 8
// 454.907 us; speedup vs baseline: 1.3968x; 1.0069x over previous
//
#include <hip/hip_runtime.h>
#include <hip/hip_bf16.h>

typedef __attribute__((ext_vector_type(8))) short short8;
typedef __attribute__((ext_vector_type(4))) float f32x4;

#define S_LEN 2048
#define DM 1024
#define NBATCH 8

__device__ __forceinline__ ushort f2b(float f) {
    union { float f; unsigned u; } a; a.f = f;
    unsigned u = a.u;
    u += 0x7fffu + ((u >> 16) & 1u);   // round-to-nearest-even
    return (ushort)(u >> 16);
}

__device__ __forceinline__ float lo2f(unsigned p) {   // low bf16 of packed u32
    union { unsigned u; float f; } a; a.u = p << 16;
    return a.f;
}
__device__ __forceinline__ float hi2f(unsigned p) {   // high bf16 of packed u32
    union { unsigned u; float f; } a; a.u = p & 0xffff0000u;
    return a.f;
}

// packed f32 pair -> bf16x2 (compiler emits v_cvt_pk_bf16_f32)
__device__ __forceinline__ unsigned pkbf(float a, float b) {
    float2 t; t.x = a; t.y = b;
    __hip_bfloat162 h = __float22bfloat162_rn(t);
    union { __hip_bfloat162 h; unsigned u; } c; c.h = h;
    return c.u;
}

#define GLDS(gp, lp) __builtin_amdgcn_global_load_lds( \
    (const __attribute__((address_space(1))) void*)(gp), \
    (__attribute__((address_space(3))) void*)(lp), 16, 0, 0)

#define BAR() __builtin_amdgcn_s_barrier()
#define VMW(N) asm volatile("s_waitcnt vmcnt(" #N ")" ::: "memory")

// one quadrant: 16 MFMA, setprio-wrapped (T5). MH/NH must be literals.
#define QUAD(AF, BF, MH, NH) do {                                              \
    __builtin_amdgcn_s_setprio(1);                                             \
    _Pragma("unroll") for (int m_ = 0; m_ < 4; m_++)                           \
    _Pragma("unroll") for (int n_ = 0; n_ < 2; n_++)                           \
    _Pragma("unroll") for (int ks_ = 0; ks_ < 2; ks_++)                        \
        acc[(MH)*4 + m_][(NH)*2 + n_] = __builtin_amdgcn_mfma_f32_16x16x32_bf16( \
            AF[m_][ks_], BF[n_][ks_], acc[(MH)*4 + m_][(NH)*2 + n_], 0, 0, 0); \
    __builtin_amdgcn_s_setprio(0);                                             \
} while (0)

// ---------------------------------------------------------------------------
// 256x256 MFMA GEMM, BK=64, 8 waves (2M x 4N), per-wave 128x64 output.
// C[M,N] = A[M,K] * B[N,K]^T (+ bias[N]); A,B bf16.
// 4 phases per K-tile: {stage half-tile | ds_read subtile | bar | 16 MFMA | bar},
// counted vmcnt(4) once per K-tile (vmcnt(0) only entering the last tile);
// post-ph3 barrier folded into the boundary barrier (VMW precedes it per-wave).
// LDS rows 128 B, XOR swizzle byte ^= ((row&7)<<4), write-linear via
// pre-swizzled global source (rule #21), read-swizzled.
// OMODE: 0 = fp32 C, 1 = bf16 C, 2 = bf16 C transposed (C[col*ldc+row]).
// ---------------------------------------------------------------------------
template<int OMODE, bool HAS_BIAS>
__global__ __launch_bounds__(512, 2) void gemm256(
    const ushort* __restrict__ A, const ushort* __restrict__ B,
    void* __restrict__ Cv, const float* __restrict__ bias,
    int K, int lda, int ldb, int ldc,
    long long sA, long long sB, long long sC)
{
    __shared__ __align__(16) ushort lA[2][2][128 * 64];   // [buf][half] 64 KB
    __shared__ __align__(16) ushort lB[2][2][128 * 64];   // 64 KB

    const int t = threadIdx.x;
    const int lane = t & 63;
    const int wid = t >> 6;
    const int wm = wid >> 2, wn = wid & 3;                // 2 x 4 wave grid
    const int z = blockIdx.z;

    // --- XCD-aware bijective swizzle (m204), bn-fastest within XCD chunk ---
    const int gx = gridDim.x, gy = gridDim.y;
    const int nwg = gx * gy;
    const int lid = blockIdx.y * gx + blockIdx.x;
    const int qq = nwg >> 3, r8 = nwg & 7;
    const int xcd = lid & 7, off = lid >> 3;
    const int w = (xcd < r8 ? xcd * (qq + 1) : r8 * (qq + 1) + (xcd - r8) * qq) + off;
    const int bm = w / gy, bn = w % gy;

    const ushort* Ap = A + (size_t)z * sA + (size_t)(bm * 256) * lda;
    const ushort* Bp = B + (size_t)z * sB + (size_t)(bn * 256) * ldb;

    f32x4 acc[8][4] = {};

    // staging map: half-tile = 128 rows x 128 B; 2 GLDS issues (64 rows each)
    const int srow = t >> 3;                               // 0..63
    const int scol = ((t & 7) ^ (srow & 7)) * 8;           // pre-swizzled col

    auto stA = [&](int kt, int h, int buf) {
        const ushort* g = Ap + (size_t)(h * 128 + srow) * lda + kt * 64 + scol;
        char* d = (char*)lA[buf][h];
        GLDS(g, d + t * 16);
        GLDS(g + (size_t)64 * lda, d + 8192 + t * 16);
    };
    auto stB = [&](int kt, int h, int buf) {
        const ushort* g = Bp + (size_t)(h * 128 + srow) * ldb + kt * 64 + scol;
        char* d = (char*)lB[buf][h];
        GLDS(g, d + t * 16);
        GLDS(g + (size_t)64 * ldb, d + 8192 + t * 16);
    };

    const int nK = K >> 6;

    // prologue: tile0 complete (8 loads) + tile1 A0,B0 (4 loads)
    stA(0, 0, 0); stB(0, 0, 0); stA(0, 1, 0); stB(0, 1, 0);
    if (nK > 1) {
        stA(1, 0, 1); stB(1, 0, 1);
        VMW(4);
    } else {
        VMW(0);
    }
    BAR();

    // read map
    const int r = lane & 15;
    const int swz = (r & 7) << 4;
    const int cb0 = ((lane >> 4) * 16) ^ swz;
    const int cb1 = (64 + (lane >> 4) * 16) ^ swz;
    const int lbr = (wn & 1) * 64;                         // local row base in B half
    const int bh = wn >> 1;                                // B half index

    int cur = 0;
    for (int kt = 0; kt < nK; ++kt) {
        const char* la = (const char*)lA[cur][wm];
        const char* lb = (const char*)lB[cur][bh];
        short8 af[4][2], b0f[2][2], b1f[2][2];

        // ---- phase 0 ----
#pragma unroll
        for (int m = 0; m < 4; m++) {
            const int lr = m * 16 + r;
            af[m][0] = *(const short8*)(la + lr * 128 + cb0);
            af[m][1] = *(const short8*)(la + lr * 128 + cb1);
        }
#pragma unroll
        for (int n = 0; n < 2; n++) {
            const int lr = lbr + n * 16 + r;
            b0f[n][0] = *(const short8*)(lb + lr * 128 + cb0);
            b0f[n][1] = *(const short8*)(lb + lr * 128 + cb1);
        }
        if (kt + 1 < nK) stA(kt + 1, 1, cur ^ 1);
        BAR();
        QUAD(af, b0f, 0, 0);
        BAR();

        // ---- phase 1 ----
#pragma unroll
        for (int n = 0; n < 2; n++) {
            const int lr = lbr + 32 + n * 16 + r;
            b1f[n][0] = *(const short8*)(lb + lr * 128 + cb0);
            b1f[n][1] = *(const short8*)(lb + lr * 128 + cb1);
        }
        if (kt + 1 < nK) stB(kt + 1, 1, cur ^ 1);
        BAR();
        QUAD(af, b1f, 0, 1);
        BAR();

        // ---- phase 2 ----
#pragma unroll
        for (int m = 0; m < 4; m++) {
            const int lr = 64 + m * 16 + r;
            af[m][0] = *(const short8*)(la + lr * 128 + cb0);
            af[m][1] = *(const short8*)(la + lr * 128 + cb1);
        }
        if (kt + 2 < nK) stB(kt + 2, 0, cur);
        BAR();
        QUAD(af, b0f, 1, 0);
        BAR();

        // ---- phase 3 ----
        if (kt + 2 < nK) stA(kt + 2, 0, cur);
        BAR();
        QUAD(af, b1f, 1, 1);

        // ---- K-tile boundary: counted wait (T4); single barrier (merged) ----
        if (kt + 1 < nK) {
            if (kt + 1 == nK - 1) { VMW(0); } else { VMW(4); }
        }
        BAR();
        cur ^= 1;
    }

    // epilogue: frag row = (lane>>4)*4 + j, col = lane&15
    const int ro = (lane >> 4) * 4;
    const int colb = bn * 256 + wn * 64;
    const int rowb = bm * 256 + wm * 128;
    float bv[4];
    if constexpr (HAS_BIAS) {
#pragma unroll
        for (int n = 0; n < 4; n++) bv[n] = bias[colb + n * 16 + r];
    }

    if constexpr (OMODE == 0) {
        float* Cp = (float*)Cv + (size_t)z * sC;
#pragma unroll
        for (int m = 0; m < 8; m++)
#pragma unroll
            for (int n = 0; n < 4; n++) {
                const int col = colb + n * 16 + r;
#pragma unroll
                for (int j = 0; j < 4; j++) {
                    float vv = acc[m][n][j];
                    if constexpr (HAS_BIAS) vv += bv[n];
                    Cp[(size_t)(rowb + m * 16 + ro + j) * ldc + col] = vv;
                }
            }
    } else if constexpr (OMODE == 1) {
        ushort* Cp = (ushort*)Cv + (size_t)z * sC;
#pragma unroll
        for (int m = 0; m < 8; m++)
#pragma unroll
            for (int n = 0; n < 4; n++) {
                const int col = colb + n * 16 + r;
#pragma unroll
                for (int j = 0; j < 4; j++) {
                    float vv = acc[m][n][j];
                    if constexpr (HAS_BIAS) vv += bv[n];
                    Cp[(size_t)(rowb + m * 16 + ro + j) * ldc + col] = f2b(vv);
                }
            }
    } else {
        // transposed bf16 store: Cp[col*ldc + row]; 4 consecutive rows -> ushort4
        ushort* Cp = (ushort*)Cv + (size_t)z * sC;
#pragma unroll
        for (int m = 0; m < 8; m++)
#pragma unroll
            for (int n = 0; n < 4; n++) {
                const int col = colb + n * 16 + r;
                float v0 = acc[m][n][0], v1 = acc[m][n][1], v2 = acc[m][n][2], v3 = acc[m][n][3];
                if constexpr (HAS_BIAS) { v0 += bv[n]; v1 += bv[n]; v2 += bv[n]; v3 += bv[n]; }
                ushort4 u;
                u.x = f2b(v0); u.y = f2b(v1); u.z = f2b(v2); u.w = f2b(v3);
                *(ushort4*)&Cp[(size_t)col * ldc + rowb + m * 16 + ro] = u;
            }
    }
}

// ---------------------------------------------------------------------------
__global__ __launch_bounds__(256) void cast_f32_bf16_k(
    const float* __restrict__ in, ushort* __restrict__ outp, int n)
{
    int idx = (blockIdx.x * 256 + threadIdx.x) * 4;
    if (idx >= n) return;
    float4 f = *(const float4*)&in[idx];
    uint2 u; u.x = pkbf(f.x, f.y); u.y = pkbf(f.z, f.w);
    *(uint2*)&outp[idx] = u;
}

// cast q,k,v -> contiguous bf16 [3][n_each]; blockIdx.y selects the input
__global__ __launch_bounds__(256) void cast3_k(
    const float* __restrict__ q, const float* __restrict__ k,
    const float* __restrict__ v, ushort* __restrict__ outp, int n_each)
{
    const float* src = (blockIdx.y == 0) ? q : (blockIdx.y == 1) ? k : v;
    ushort* dst = outp + (size_t)blockIdx.y * n_each;
    const int stride = gridDim.x * 256 * 4;
    for (int idx = (blockIdx.x * 256 + threadIdx.x) * 4; idx < n_each; idx += stride) {
        float4 f = *(const float4*)&src[idx];
        uint2 u; u.x = pkbf(f.x, f.y); u.y = pkbf(f.z, f.w);
        *(uint2*)&dst[idx] = u;
    }
}

// ---------------------------------------------------------------------------
// Masked softmax: reads bf16 scores (row length 2048) as packed u32 pairs,
// x = score/32, masked -> -1e9 exactly, row softmax.
// Writes fp32 weights + bf16 copy.
// ---------------------------------------------------------------------------
__global__ __launch_bounds__(256) void softmax_rows(
    const ushort* __restrict__ sc, const int* __restrict__ mask,
    float* __restrict__ w, ushort* __restrict__ wb)
{
    __shared__ float red[8];
    const int rid = blockIdx.x;            // b*S + q
    const int b = rid >> 11;               // S = 2048
    const ushort* srow = sc + (size_t)rid * S_LEN;
    float* row = w + (size_t)rid * S_LEN;
    ushort* brow = wb + (size_t)rid * S_LEN;
    const int* mrow = mask + (size_t)b * S_LEN;
    const int t = threadIdx.x;
    const int wid = t >> 6, lane = t & 63;
    const float scale = 0.03125f;          // 1/sqrt(1024)

    const int idx = t * 8;
    uint4 s4 = *(const uint4*)&srow[idx];       // 8 bf16 scores packed
    int4 m0 = *(const int4*)&mrow[idx];
    int4 m1 = *(const int4*)&mrow[idx + 4];

    float x[8];
    x[0] = (m0.x == 0) ? -1.0e9f : lo2f(s4.x) * scale;
    x[1] = (m0.y == 0) ? -1.0e9f : hi2f(s4.x) * scale;
    x[2] = (m0.z == 0) ? -1.0e9f : lo2f(s4.y) * scale;
    x[3] = (m0.w == 0) ? -1.0e9f : hi2f(s4.y) * scale;
    x[4] = (m1.x == 0) ? -1.0e9f : lo2f(s4.z) * scale;
    x[5] = (m1.y == 0) ? -1.0e9f : hi2f(s4.z) * scale;
    x[6] = (m1.z == 0) ? -1.0e9f : lo2f(s4.w) * scale;
    x[7] = (m1.w == 0) ? -1.0e9f : hi2f(s4.w) * scale;

    float mx = fmaxf(fmaxf(fmaxf(x[0], x[1]), fmaxf(x[2], x[3])),
                     fmaxf(fmaxf(x[4], x[5]), fmaxf(x[6], x[7])));
#pragma unroll
    for (int off = 32; off; off >>= 1) mx = fmaxf(mx, __shfl_xor(mx, off));
    if (lane == 0) red[wid] = mx;
    __syncthreads();
    mx = fmaxf(fmaxf(red[0], red[1]), fmaxf(red[2], red[3]));

    float sum = 0.0f;
#pragma unroll
    for (int i = 0; i < 8; i++) { x[i] = __expf(x[i] - mx); sum += x[i]; }
#pragma unroll
    for (int off = 32; off; off >>= 1) sum += __shfl_xor(sum, off);
    if (lane == 0) red[4 + wid] = sum;
    __syncthreads();
    sum = red[4] + red[5] + red[6] + red[7];
    const float inv = 1.0f / sum;

    float4 o0, o1;
    o0.x = x[0] * inv; o0.y = x[1] * inv; o0.z = x[2] * inv; o0.w = x[3] * inv;
    o1.x = x[4] * inv; o1.y = x[5] * inv; o1.z = x[6] * inv; o1.w = x[7] * inv;
    *(float4*)&row[idx] = o0;
    *(float4*)&row[idx + 4] = o1;
    uint4 ub;
    ub.x = pkbf(o0.x, o0.y); ub.y = pkbf(o0.z, o0.w);
    ub.z = pkbf(o1.x, o1.y); ub.w = pkbf(o1.z, o1.w);
    *(uint4*)&brow[idx] = ub;
}

// ---------------------------------------------------------------------------
extern "C" void kernel_launch(void* const* d_in, const int* in_sizes, int n_in,
                              void* d_out, int out_size, void* d_ws, size_t ws_size,
                              hipStream_t stream)
{
    const float* q    = (const float*)d_in[0];
    const float* k    = (const float*)d_in[1];
    const float* v    = (const float*)d_in[2];
    const int*   mask = (const int*)d_in[3];
    const float* Wq   = (const float*)d_in[4];
    const float* bq   = (const float*)d_in[5];
    const float* Wout = (const float*)d_in[6];
    const float* bout = (const float*)d_in[7];

    float* out     = (float*)d_out;                             // [8,2048,1024] fp32
    float* weights = out + (size_t)NBATCH * S_LEN * DM;         // [8,2048,2048] fp32

    const size_t NTOK = (size_t)NBATCH * S_LEN;                 // 16384

    // Overlays of dead d_out regions:
    // 1) bf16 q/k/v casts live in the weights region (134 MB; dead until softmax)
    ushort* qkvb = (ushort*)weights;                            // [3][16384*1024] bf16
    ushort* qb = qkvb;
    ushort* kb = qb + NTOK * DM;
    ushort* vb = kb + NTOK * DM;
    // 2) bf16 softmax weights live in the out region (67 MB; dead until outproj)
    ushort* wbf = (ushort*)d_out;

    ushort* qp    = (ushort*)d_ws;                              // [16384,1024] bf16
    ushort* kp    = qp + NTOK * DM;
    ushort* vpT   = kp + NTOK * DM;                             // [8,1024,2048] bf16
    ushort* attn  = qp;                                         // alias: qp dead after scores
    ushort* Wqb   = vpT + NTOK * DM;
    ushort* Woutb = Wqb + (size_t)DM * DM;
    ushort* scb   = Woutb + (size_t)DM * DM;                    // [8,2048,2048] bf16 scores

    dim3 blk(256, 1, 1);
    dim3 blk5(512, 1, 1);

    cast_f32_bf16_k<<<dim3(1024, 1, 1), blk, 0, stream>>>(Wq, Wqb, DM * DM);
    cast_f32_bf16_k<<<dim3(1024, 1, 1), blk, 0, stream>>>(Wout, Woutb, DM * DM);
    cast3_k<<<dim3(2048, 3, 1), blk, 0, stream>>>(q, k, v, qkvb, (int)(NTOK * DM));

    // q,k projections: [16384,1024] x Wq[1024,1024]^T + bq -> bf16
    gemm256<1, true><<<dim3(64, 4, 1), blk5, 0, stream>>>(
        qb, Wqb, qp, bq, 1024, 1024, 1024, 1024, 0, 0, 0);
    gemm256<1, true><<<dim3(64, 4, 1), blk5, 0, stream>>>(
        kb, Wqb, kp, bq, 1024, 1024, 1024, 1024, 0, 0, 0);
    // v projection, stored transposed per batch: vpT[b][d][s]
    gemm256<2, true><<<dim3(8, 4, NBATCH), blk5, 0, stream>>>(
        vb, Wqb, vpT, bq, 1024, 1024, 1024, 2048,
        (long long)S_LEN * DM, 0, (long long)DM * S_LEN);

    // scores = qp * kp^T -> bf16 scratch scb (raw scores; scale+mask in softmax)
    gemm256<1, false><<<dim3(8, 8, NBATCH), blk5, 0, stream>>>(
        qp, kp, scb, nullptr, 1024, 1024, 1024, 2048,
        (long long)S_LEN * DM, (long long)S_LEN * DM, (long long)S_LEN * S_LEN);

    // masked softmax: bf16 scores -> fp32 weights (d_out) + bf16 copy (wbf)
    softmax_rows<<<dim3(NBATCH * S_LEN, 1, 1), blk, 0, stream>>>(scb, mask, weights, wbf);

    // attn = softmax(weights) * vp   (A = wbf bf16, B = vpT in N x K layout)
    gemm256<1, false><<<dim3(8, 4, NBATCH), blk5, 0, stream>>>(
        wbf, vpT, attn, nullptr, 2048, 2048, 2048, 1024,
        (long long)S_LEN * S_LEN, (long long)DM * S_LEN, (long long)S_LEN * DM);

    // out = attn * Wout^T + bout -> fp32 (overwrites the wbf overlay)
    gemm256<0, true><<<dim3(64, 4, 1), blk5, 0, stream>>>(
        attn, Woutb, out, bout, 1024, 1024, 1024, 1024, 0, 0, 0);
}